// Round 5
// baseline (1308.944 us; speedup 1.0000x reference)
//
#include <hip/hip_runtime.h>
#include <hip/hip_bf16.h>
#include <cstdint>

// ---------------------------------------------------------------------------
// Qwen3.5 GatedDeltaNet — round 5: recur phase-3 rework (register diagonal
// solve, padded LDS). GEMMs/conv/norm unchanged from round 4.
// ---------------------------------------------------------------------------

#define HSZ 2048
#define NUM_K_HEADS 16
#define NUM_V_HEADS 32
#define DKH 128
#define DVH 128
#define KEY_DIM 2048
#define VALUE_DIM 4096
#define CONV_DIM 8192
#define BB 2
#define SSEQ 2048
#define MM (BB * SSEQ) /* 4096 rows */
#define CHUNK 64
#define NCHUNK (SSEQ / CHUNK) /* 32 */

typedef __hip_bfloat16 bf16;
typedef short short8 __attribute__((ext_vector_type(8)));
typedef float f32x4 __attribute__((ext_vector_type(4)));

__device__ __forceinline__ float bfu(ushort u) {
  union { float f; uint32_t i; } x;
  x.i = ((uint32_t)u) << 16;
  return x.f;
}
__device__ __forceinline__ ushort f2b(float f) {
  bf16 h = __float2bfloat16(f);
  return *reinterpret_cast<ushort*>(&h);
}

__device__ __forceinline__ void gload16(const void* g, const void* l) {
  __builtin_amdgcn_global_load_lds(
      (const __attribute__((address_space(1))) unsigned int*)g,
      (__attribute__((address_space(3))) unsigned int*)(const_cast<void*>(l)),
      16, 0, 0);
}

// swizzled LDS indexers (break D=128/D=64 row-major bank pathology)
__device__ __forceinline__ int kidx(int r, int d) {  // [*][128] bf16
  return r * 128 + (((d >> 3) ^ (r & 7)) << 3) + (d & 7);
}
__device__ __forceinline__ int widx(int r, int d) {  // [*][64] bf16
  return r * 64 + (((d >> 3) ^ (r & 7)) << 3) + (d & 7);
}

// padded fp32 strides
#define ALD 65
#define ULD 34
#define SLD 33

// ---------------- cast fp32 -> bf16 ----------------------------------------
__global__ __launch_bounds__(256) void cast_bf16_kernel(
    const float* __restrict__ in, ushort* __restrict__ out, int n4) {
  int i = blockIdx.x * 256 + threadIdx.x;
  if (i < n4) {
    float4 v = ((const float4*)in)[i];
    ushort4 u;
    u.x = f2b(v.x); u.y = f2b(v.y); u.z = f2b(v.z); u.w = f2b(v.w);
    ((ushort4*)out)[i] = u;
  }
}

// ---------------- transpose + cast: W[K,N] fp32 -> WT[N,K] bf16 ------------
__global__ __launch_bounds__(256) void transpose_cast(
    const float* __restrict__ W, ushort* __restrict__ WT, int K, int N) {
  __shared__ ushort tile[32][33];
  const int tx = threadIdx.x & 31, ty = threadIdx.x >> 5;
  const int n0 = blockIdx.x * 32, k0 = blockIdx.y * 32;
#pragma unroll
  for (int i = 0; i < 4; ++i)
    tile[ty + i * 8][tx] = f2b(W[(size_t)(k0 + ty + i * 8) * N + n0 + tx]);
  __syncthreads();
#pragma unroll
  for (int i = 0; i < 4; ++i)
    WT[(size_t)(n0 + ty + i * 8) * K + k0 + tx] = tile[tx][ty + i * 8];
}

// ---------------- bf16 MFMA GEMM: C[M,N] = A[M,K] @ BT[N,K]^T --------------
template <bool BF16_OUT>
__global__ __launch_bounds__(256) void gemm_mfma(
    const ushort* __restrict__ A, const ushort* __restrict__ BT,
    void* __restrict__ Cv, int M, int N, int K) {
  __shared__ ushort As[128 * 64];
  __shared__ ushort Bs[128 * 64];
  const int t = threadIdx.x;
  const int w = t >> 6, lane = t & 63;
  const int m0 = blockIdx.y * 128, n0 = blockIdx.x * 128;
  const int srow = lane >> 3;
  const int scol = (lane & 7) * 8;
  const int wm = (w >> 1) * 64, wn = (w & 1) * 64;
  const int fr = lane & 15, kb = lane >> 4;
  f32x4 acc[4][4] = {};

  for (int k0 = 0; k0 < K; k0 += 64) {
#pragma unroll
    for (int i = 0; i < 4; ++i) {
      const int row = (i * 4 + w) * 8 + srow;
      gload16(&A[(size_t)(m0 + row) * K + k0 + scol], &As[row * 64 + scol]);
      gload16(&BT[(size_t)(n0 + row) * K + k0 + scol], &Bs[row * 64 + scol]);
    }
    __syncthreads();
#pragma unroll
    for (int ks = 0; ks < 2; ++ks) {
      const int ka = ks * 32 + kb * 8;
      short8 af[4], bfr[4];
#pragma unroll
      for (int mf = 0; mf < 4; ++mf)
        af[mf] = *(const short8*)&As[(wm + mf * 16 + fr) * 64 + ka];
#pragma unroll
      for (int nf = 0; nf < 4; ++nf)
        bfr[nf] = *(const short8*)&Bs[(wn + nf * 16 + fr) * 64 + ka];
#pragma unroll
      for (int mf = 0; mf < 4; ++mf)
#pragma unroll
        for (int nf = 0; nf < 4; ++nf)
          acc[mf][nf] = __builtin_amdgcn_mfma_f32_16x16x32_bf16(
              af[mf], bfr[nf], acc[mf][nf], 0, 0, 0);
    }
    __syncthreads();
  }
  const int orow = m0 + wm + (lane >> 4) * 4;
  const int ocol = n0 + wn + fr;
#pragma unroll
  for (int mf = 0; mf < 4; ++mf)
#pragma unroll
    for (int nf = 0; nf < 4; ++nf)
#pragma unroll
      for (int j = 0; j < 4; ++j) {
        const size_t off = (size_t)(orow + mf * 16 + j) * N + ocol + nf * 16;
        if constexpr (BF16_OUT)
          ((ushort*)Cv)[off] = f2b(acc[mf][nf][j]);
        else
          ((float*)Cv)[off] = acc[mf][nf][j];
      }
}

// ---------------- b/a projections + gates (g = log decay) ------------------
__global__ __launch_bounds__(256) void ba_kernel(
    const float* __restrict__ hs, const float* __restrict__ w_b,
    const float* __restrict__ w_a, const float* __restrict__ dt_bias,
    const float* __restrict__ A_log, float* __restrict__ gbuf,
    float* __restrict__ beta) {
  const int row = blockIdx.x;
  const int t = threadIdx.x;
  __shared__ float hsrow[HSZ];
  __shared__ float rb[256], ra[256];
  for (int c = t; c < HSZ; c += 256) hsrow[c] = hs[(size_t)row * HSZ + c];
  __syncthreads();
  const int h = t & 31, p = t >> 5;
  float sb = 0.f, sa = 0.f;
  const int kbeg = p * 256;
  for (int k = kbeg; k < kbeg + 256; ++k) {
    float x = hsrow[k];
    sb += x * w_b[k * NUM_V_HEADS + h];
    sa += x * w_a[k * NUM_V_HEADS + h];
  }
  rb[t] = sb;
  ra[t] = sa;
  __syncthreads();
  if (t < NUM_V_HEADS) {
    float b = 0.f, a = 0.f;
#pragma unroll
    for (int q = 0; q < 8; ++q) {
      b += rb[t + 32 * q];
      a += ra[t + 32 * q];
    }
    float bet = 1.f / (1.f + expf(-b));
    float x = a + dt_bias[t];
    float sp = (x > 20.f) ? x : log1pf(expf(x));
    gbuf[(size_t)row * NUM_V_HEADS + t] = -expf(A_log[t]) * sp;
    beta[(size_t)row * NUM_V_HEADS + t] = bet;
  }
}

// ---------------- causal conv + silu + l2norm (bf16) -----------------------
__global__ __launch_bounds__(256) void conv_kernel(
    const ushort* __restrict__ mixed, const float* __restrict__ conv_w,
    ushort* __restrict__ qkv) {
  const int row = blockIdx.x;
  const int s = row & (SSEQ - 1);
  const int t = threadIdx.x;
  __shared__ float buf[CONV_DIM];
  const ushort* mrow = mixed + (size_t)row * CONV_DIM;
  for (int c = t; c < CONV_DIM; c += 256) {
    float accv = 0.f;
#pragma unroll
    for (int j = 0; j < 4; ++j) {
      int ds = s - 3 + j;
      if (ds >= 0)
        accv += bfu(mrow[(ptrdiff_t)(ds - s) * CONV_DIM + c]) * conv_w[c * 4 + j];
    }
    buf[c] = accv / (1.f + expf(-accv));
  }
  __syncthreads();
  const int grp = t >> 3, r = t & 7;
  const float* gp = buf + grp * DKH + r * 16;
  float ssq = 0.f;
#pragma unroll
  for (int i = 0; i < 16; ++i) {
    float x = gp[i];
    ssq += x * x;
  }
  ssq += __shfl_xor(ssq, 1, 64);
  ssq += __shfl_xor(ssq, 2, 64);
  ssq += __shfl_xor(ssq, 4, 64);
  float sc = rsqrtf(ssq + 1e-6f);
  if (grp < 16) sc *= 0.08838834764831845f;
  ushort* orow = qkv + (size_t)row * CONV_DIM;
#pragma unroll
  for (int i = 0; i < 16; ++i) orow[grp * DKH + r * 16 + i] = f2b(gp[i] * sc);
  for (int c = 2 * KEY_DIM + t; c < CONV_DIM; c += 256) orow[c] = f2b(buf[c]);
}

// ---------------- chunked gated delta rule (WY form) -----------------------
// grid = 256 blocks: (b:2) x (h:32) x (dvq:4, 32 v-cols each). 256 thr.
__global__ __launch_bounds__(256) void recur_chunk_kernel(
    const ushort* __restrict__ qkv, const float* __restrict__ gbuf,
    const float* __restrict__ beta, float* __restrict__ o) {
  const int bid = blockIdx.x;
  const int dvq = bid & 3;
  const int h = (bid >> 2) & 31;
  const int b = bid >> 7;
  const int hk = h >> 1;
  const int t = threadIdx.x;
  const int w = t >> 6, lane = t & 63;
  const int fr = lane & 15, fq = lane >> 4;

  __shared__ ushort Klds[64 * 128];
  __shared__ ushort Qlds[64 * 128];
  __shared__ ushort Vlds[64 * 32];
  __shared__ float Slds[128 * SLD];
  __shared__ ushort Sth[32 * 128];
  __shared__ ushort Stl[32 * 128];
  __shared__ float Alds[64 * ALD];
  __shared__ float Ulds[64 * ULD];
  __shared__ ushort UTs[32 * 64];  // exp(G63-Gi)*u — state update operand
  __shared__ ushort UTo[32 * 64];  // plain u — output operand
  __shared__ ushort Wb[64 * 64];
  __shared__ float Gs[64], Bsh[64];

  for (int i = t; i < 128 * 32; i += 256) Slds[(i >> 5) * SLD + (i & 31)] = 0.f;
  __syncthreads();

  const int qcol = hk * DKH;
  const int kcol = KEY_DIM + hk * DKH;
  const int vcol = 2 * KEY_DIM + h * DVH + dvq * 32;

  for (int c = 0; c < NCHUNK; ++c) {
    const int row0 = b * SSEQ + c * CHUNK;

    // ---- phase 1: load K/Q (swizzled), V; gates + scan; S -> hi/lo -------
#pragma unroll
    for (int r = 0; r < 4; ++r) {
      int vi = t + 256 * r;
      int row = vi >> 4, gr = vi & 15;
      const size_t gb = (size_t)(row0 + row) * CONV_DIM;
      short8 kv = *(const short8*)&qkv[gb + kcol + gr * 8];
      short8 qv = *(const short8*)&qkv[gb + qcol + gr * 8];
      *(short8*)&Klds[row * 128 + ((gr ^ (row & 7)) << 3)] = kv;
      *(short8*)&Qlds[row * 128 + ((gr ^ (row & 7)) << 3)] = qv;
    }
    {
      int row = t >> 2, gr = t & 3;
      *(short8*)&Vlds[row * 32 + gr * 8] =
          *(const short8*)&qkv[(size_t)(row0 + row) * CONV_DIM + vcol + gr * 8];
    }
    if (t < 64) {
      float s = gbuf[(size_t)(row0 + t) * NUM_V_HEADS + h];
#pragma unroll
      for (int off = 1; off < 64; off <<= 1) {
        float p = __shfl_up(s, off, 64);
        if (lane >= off) s += p;
      }
      Gs[t] = s;
      Bsh[t] = beta[(size_t)(row0 + t) * NUM_V_HEADS + h];
    }
    {
      int v = t & 31, dk0 = (t >> 5) * 16;
#pragma unroll
      for (int e = 0; e < 16; ++e) {
        int d = dk0 + e;
        float f = Slds[d * SLD + v];
        ushort hi = f2b(f);
        float rem = f - bfu(hi);
        int idx = kidx(v, d);
        Sth[idx] = hi;
        Stl[idx] = f2b(rem);
      }
    }
    __syncthreads();

    // ---- phase 2: KK^T -> A ; K@S0 -> U init -----------------------------
    {
      f32x4 kkt[4] = {};
      f32x4 ks0[2] = {};
#pragma unroll
      for (int ks = 0; ks < 4; ++ks) {
        int d0 = ks * 32 + fq * 8;
        short8 xk = *(const short8*)&Klds[kidx(w * 16 + fr, d0)];
#pragma unroll
        for (int j = 0; j < 4; ++j) {
          short8 yk = *(const short8*)&Klds[kidx(j * 16 + fr, d0)];
          kkt[j] = __builtin_amdgcn_mfma_f32_16x16x32_bf16(xk, yk, kkt[j], 0, 0, 0);
        }
#pragma unroll
        for (int vt = 0; vt < 2; ++vt) {
          short8 yh = *(const short8*)&Sth[kidx(vt * 16 + fr, d0)];
          short8 yl = *(const short8*)&Stl[kidx(vt * 16 + fr, d0)];
          ks0[vt] = __builtin_amdgcn_mfma_f32_16x16x32_bf16(xk, yh, ks0[vt], 0, 0, 0);
          ks0[vt] = __builtin_amdgcn_mfma_f32_16x16x32_bf16(xk, yl, ks0[vt], 0, 0, 0);
        }
      }
#pragma unroll
      for (int j = 0; j < 4; ++j)
#pragma unroll
        for (int jj = 0; jj < 4; ++jj) {
          int i = w * 16 + fq * 4 + jj;
          int jc = j * 16 + fr;
          Alds[i * ALD + jc] =
              (jc < i) ? Bsh[i] * __expf(Gs[i] - Gs[jc]) * kkt[j][jj] : 0.f;
        }
#pragma unroll
      for (int vt = 0; vt < 2; ++vt)
#pragma unroll
        for (int jj = 0; jj < 4; ++jj) {
          int i = w * 16 + fq * 4 + jj;
          int v = vt * 16 + fr;
          Ulds[i * ULD + v] =
              Bsh[i] * (bfu(Vlds[i * 32 + v]) - __expf(Gs[i]) * ks0[vt][jj]);
        }
    }
    __syncthreads();

    // ---- phase 3: forward substitution (I+A) U = RHS ---------------------
    // off-diag: 256-thread MFMA-free fp32 correction; diag: lane-per-column
    // register solve (dependency chain stays in VGPRs, no LDS round-trip).
    for (int ib = 0; ib < 4; ++ib) {
      if (ib > 0) {
        const int r = t >> 4, c0 = (t & 15) * 2;
        const int irow = ib * 16 + r;
        float a0 = 0.f, a1 = 0.f;
        const int jmax = ib * 16;
        for (int j = 0; j < jmax; ++j) {
          float a = Alds[irow * ALD + j];
          a0 += a * Ulds[j * ULD + c0];
          a1 += a * Ulds[j * ULD + c0 + 1];
        }
        Ulds[irow * ULD + c0] -= a0;
        Ulds[irow * ULD + c0 + 1] -= a1;
        __syncthreads();
      }
      if (t < 32) {
        float u[16];
#pragma unroll
        for (int i = 0; i < 16; ++i) u[i] = Ulds[(ib * 16 + i) * ULD + t];
#pragma unroll
        for (int j = 0; j < 15; ++j) {
          float uj = u[j];
#pragma unroll
          for (int i = 0; i < 16; ++i)
            if (i > j)
              u[i] -= Alds[(ib * 16 + i) * ALD + ib * 16 + j] * uj;
        }
#pragma unroll
        for (int i = 1; i < 16; ++i) Ulds[(ib * 16 + i) * ULD + t] = u[i];
      }
      __syncthreads();
    }

    // ---- phase 4: U transposes; QK^T -> W; Q@S0 --------------------------
    {
      int i = t & 63, v0 = (t >> 6) * 8;
      float sc = __expf(Gs[63] - Gs[i]);
#pragma unroll
      for (int e = 0; e < 8; ++e) {
        float u = Ulds[i * ULD + v0 + e];
        int idx = widx(v0 + e, i);
        UTs[idx] = f2b(u * sc);
        UTo[idx] = f2b(u);
      }
    }
    f32x4 oacc[2] = {};
    {
      f32x4 qkt[4] = {};
#pragma unroll
      for (int ks = 0; ks < 4; ++ks) {
        int d0 = ks * 32 + fq * 8;
        short8 xq = *(const short8*)&Qlds[kidx(w * 16 + fr, d0)];
#pragma unroll
        for (int j = 0; j < 4; ++j) {
          short8 yk = *(const short8*)&Klds[kidx(j * 16 + fr, d0)];
          qkt[j] = __builtin_amdgcn_mfma_f32_16x16x32_bf16(xq, yk, qkt[j], 0, 0, 0);
        }
#pragma unroll
        for (int vt = 0; vt < 2; ++vt) {
          short8 yh = *(const short8*)&Sth[kidx(vt * 16 + fr, d0)];
          short8 yl = *(const short8*)&Stl[kidx(vt * 16 + fr, d0)];
          oacc[vt] = __builtin_amdgcn_mfma_f32_16x16x32_bf16(xq, yh, oacc[vt], 0, 0, 0);
          oacc[vt] = __builtin_amdgcn_mfma_f32_16x16x32_bf16(xq, yl, oacc[vt], 0, 0, 0);
        }
      }
#pragma unroll
      for (int j = 0; j < 4; ++j)
#pragma unroll
        for (int jj = 0; jj < 4; ++jj) {
          int tt = w * 16 + fq * 4 + jj;
          int i = j * 16 + fr;
          float val = (i <= tt) ? __expf(Gs[tt] - Gs[i]) * qkt[j][jj] : 0.f;
          Wb[widx(tt, i)] = f2b(val);
        }
#pragma unroll
      for (int vt = 0; vt < 2; ++vt)
#pragma unroll
        for (int jj = 0; jj < 4; ++jj)
          oacc[vt][jj] *= __expf(Gs[w * 16 + fq * 4 + jj]);
    }
    __syncthreads();

    // ---- phase 5: O = Lt*(QS0) + W @ U ; store; scale S ------------------
#pragma unroll
    for (int ks = 0; ks < 2; ++ks) {
      int i0 = ks * 32 + fq * 8;
      int trow = w * 16 + fr;
      short8 xw = *(const short8*)&Wb[trow * 64 + (((i0 >> 3) ^ (trow & 7)) << 3)];
#pragma unroll
      for (int vt = 0; vt < 2; ++vt) {
        int vrow = vt * 16 + fr;
        short8 yu = *(const short8*)&UTo[vrow * 64 + (((i0 >> 3) ^ (vrow & 7)) << 3)];
        oacc[vt] = __builtin_amdgcn_mfma_f32_16x16x32_bf16(xw, yu, oacc[vt], 0, 0, 0);
      }
    }
#pragma unroll
    for (int vt = 0; vt < 2; ++vt)
#pragma unroll
      for (int jj = 0; jj < 4; ++jj) {
        int tt = w * 16 + fq * 4 + jj;
        o[(size_t)(row0 + tt) * VALUE_DIM + h * DVH + dvq * 32 + vt * 16 + fr] =
            oacc[vt][jj];
      }
    {
      float eGC = __expf(Gs[63]);
      for (int i = t; i < 128 * 32; i += 256)
        Slds[(i >> 5) * SLD + (i & 31)] *= eGC;
    }
    __syncthreads();

    // ---- phase 6: S += K^T @ Us ------------------------------------------
    {
      f32x4 sacc[2][2];
#pragma unroll
      for (int dt = 0; dt < 2; ++dt) {
        int dk0 = (w * 2 + dt) * 16;
#pragma unroll
        for (int vt = 0; vt < 2; ++vt)
#pragma unroll
          for (int jj = 0; jj < 4; ++jj)
            sacc[dt][vt][jj] = Slds[(dk0 + fq * 4 + jj) * SLD + vt * 16 + fr];
#pragma unroll
        for (int ks = 0; ks < 2; ++ks) {
          short8 xk;
          int dkr = dk0 + fr;
#pragma unroll
          for (int e = 0; e < 8; ++e)
            xk[e] = (short)Klds[kidx(ks * 32 + fq * 8 + e, dkr)];
#pragma unroll
          for (int vt = 0; vt < 2; ++vt) {
            int vrow = vt * 16 + fr;
            int i0 = ks * 32 + fq * 8;
            short8 yu =
                *(const short8*)&UTs[vrow * 64 + (((i0 >> 3) ^ (vrow & 7)) << 3)];
            sacc[dt][vt] = __builtin_amdgcn_mfma_f32_16x16x32_bf16(
                xk, yu, sacc[dt][vt], 0, 0, 0);
          }
        }
#pragma unroll
        for (int vt = 0; vt < 2; ++vt)
#pragma unroll
          for (int jj = 0; jj < 4; ++jj)
            Slds[(dk0 + fq * 4 + jj) * SLD + vt * 16 + fr] = sacc[dt][vt][jj];
      }
    }
    __syncthreads();
  }
}

// ---------------- gated RMSNorm -> bf16 ------------------------------------
__global__ __launch_bounds__(256) void gnorm_kernel(
    const float* __restrict__ o, const ushort* __restrict__ z,
    const float* __restrict__ gamma, ushort* __restrict__ ob) {
  const int row = blockIdx.x;
  const int t = threadIdx.x;
  const int grp = t >> 3, r = t & 7;
  const float* op = o + (size_t)row * VALUE_DIM + grp * DVH + r * 16;
  const ushort* zp = z + (size_t)row * VALUE_DIM + grp * DVH + r * 16;
  ushort* obp = ob + (size_t)row * VALUE_DIM + grp * DVH + r * 16;
  float vals[16];
  float ssq = 0.f;
#pragma unroll
  for (int i = 0; i < 16; ++i) {
    float zz = bfu(zp[i]);
    float x = op[i] * (zz / (1.f + expf(-zz)));
    vals[i] = x;
    ssq += x * x;
  }
  ssq += __shfl_xor(ssq, 1, 64);
  ssq += __shfl_xor(ssq, 2, 64);
  ssq += __shfl_xor(ssq, 4, 64);
  float sc = rsqrtf(ssq * (1.f / 128.f) + 1e-6f);
#pragma unroll
  for (int i = 0; i < 16; ++i) obp[i] = f2b(vals[i] * sc * gamma[r * 16 + i]);
}

// ---------------------------------------------------------------------------
extern "C" void kernel_launch(void* const* d_in, const int* in_sizes, int n_in,
                              void* d_out, int out_size, void* d_ws,
                              size_t ws_size, hipStream_t stream) {
  const float* hs = (const float*)d_in[0];
  const float* w_qkv = (const float*)d_in[1];
  const float* w_z = (const float*)d_in[2];
  const float* w_b = (const float*)d_in[3];
  const float* w_a = (const float*)d_in[4];
  const float* conv_w = (const float*)d_in[5];
  const float* dt_bias = (const float*)d_in[6];
  const float* A_log = (const float*)d_in[7];
  const float* gamma = (const float*)d_in[8];
  const float* w_out = (const float*)d_in[9];
  float* out = (float*)d_out;
  char* wsb = (char*)d_ws;

  // workspace layout (241 MiB total)
  ushort* hs_b = (ushort*)wsb;                      // 16 MiB
  ushort* wqkvT = hs_b + (size_t)MM * HSZ;          // 32 MiB
  ushort* wzT = wqkvT + (size_t)CONV_DIM * HSZ;     // 16 MiB
  ushort* woutT = wzT + (size_t)VALUE_DIM * HSZ;    // 16 MiB
  ushort* mixed = woutT + (size_t)HSZ * VALUE_DIM;  // 64 MiB bf16
  ushort* qkv = mixed + (size_t)MM * CONV_DIM;      // 64 MiB bf16
  ushort* z = qkv + (size_t)MM * CONV_DIM;          // 32 MiB bf16
  float* gbuf = (float*)(z + (size_t)MM * VALUE_DIM);
  float* beta = gbuf + (size_t)MM * NUM_V_HEADS;
  float* o = (float*)mixed;  // fp32, aliases retired mixed (64 MiB)
  ushort* ob = qkv;          // bf16, aliases retired qkv

  cast_bf16_kernel<<<(MM * HSZ / 4 + 255) / 256, 256, 0, stream>>>(
      hs, hs_b, MM * HSZ / 4);
  transpose_cast<<<dim3(CONV_DIM / 32, HSZ / 32), 256, 0, stream>>>(
      w_qkv, wqkvT, HSZ, CONV_DIM);
  transpose_cast<<<dim3(VALUE_DIM / 32, HSZ / 32), 256, 0, stream>>>(
      w_z, wzT, HSZ, VALUE_DIM);
  transpose_cast<<<dim3(HSZ / 32, VALUE_DIM / 32), 256, 0, stream>>>(
      w_out, woutT, VALUE_DIM, HSZ);

  gemm_mfma<true><<<dim3(CONV_DIM / 128, MM / 128), 256, 0, stream>>>(
      hs_b, wqkvT, mixed, MM, CONV_DIM, HSZ);
  gemm_mfma<true><<<dim3(VALUE_DIM / 128, MM / 128), 256, 0, stream>>>(
      hs_b, wzT, z, MM, VALUE_DIM, HSZ);
  ba_kernel<<<MM, 256, 0, stream>>>(hs, w_b, w_a, dt_bias, A_log, gbuf, beta);
  conv_kernel<<<MM, 256, 0, stream>>>(mixed, conv_w, qkv);
  recur_chunk_kernel<<<256, 256, 0, stream>>>(qkv, gbuf, beta, o);
  gnorm_kernel<<<MM, 256, 0, stream>>>(o, z, gamma, ob);
  gemm_mfma<false><<<dim3(HSZ / 128, MM / 128), 256, 0, stream>>>(
      ob, woutT, out, MM, HSZ, VALUE_DIM);
}

// Round 6
// 1204.769 us; speedup vs baseline: 1.0865x; 1.0865x over previous
//
#include <hip/hip_runtime.h>
#include <hip/hip_bf16.h>
#include <cstdint>

// ---------------------------------------------------------------------------
// Qwen3.5 GatedDeltaNet — round 6: recur rework for latency hiding.
//  grid 512 (dv split x8, DV=16/block), S-state in registers, LDS ~75KB ->
//  2 blocks/CU; 5 barriers/chunk; wave-0 in-register triangular solve
//  overlapped with W-build on waves 1-3. Other kernels unchanged.
// ---------------------------------------------------------------------------

#define HSZ 2048
#define NUM_K_HEADS 16
#define NUM_V_HEADS 32
#define DKH 128
#define DVH 128
#define KEY_DIM 2048
#define VALUE_DIM 4096
#define CONV_DIM 8192
#define BB 2
#define SSEQ 2048
#define MM (BB * SSEQ) /* 4096 rows */
#define CHUNK 64
#define NCHUNK (SSEQ / CHUNK) /* 32 */
#define DVB 16 /* v-cols per recur block */

typedef __hip_bfloat16 bf16;
typedef short short8 __attribute__((ext_vector_type(8)));
typedef float f32x4 __attribute__((ext_vector_type(4)));

__device__ __forceinline__ float bfu(ushort u) {
  union { float f; uint32_t i; } x;
  x.i = ((uint32_t)u) << 16;
  return x.f;
}
__device__ __forceinline__ ushort f2b(float f) {
  bf16 h = __float2bfloat16(f);
  return *reinterpret_cast<ushort*>(&h);
}

__device__ __forceinline__ void gload16(const void* g, const void* l) {
  __builtin_amdgcn_global_load_lds(
      (const __attribute__((address_space(1))) unsigned int*)g,
      (__attribute__((address_space(3))) unsigned int*)(const_cast<void*>(l)),
      16, 0, 0);
}

// swizzled LDS indexers (break D=128/D=64 row-major bank pathology)
__device__ __forceinline__ int kidx(int r, int d) {  // [*][128] bf16
  return r * 128 + (((d >> 3) ^ (r & 7)) << 3) + (d & 7);
}
__device__ __forceinline__ int widx(int r, int d) {  // [*][64] bf16
  return r * 64 + (((d >> 3) ^ (r & 7)) << 3) + (d & 7);
}

// padded fp32 strides
#define ALD 65
#define ULD 17

// ---------------- cast fp32 -> bf16 ----------------------------------------
__global__ __launch_bounds__(256) void cast_bf16_kernel(
    const float* __restrict__ in, ushort* __restrict__ out, int n4) {
  int i = blockIdx.x * 256 + threadIdx.x;
  if (i < n4) {
    float4 v = ((const float4*)in)[i];
    ushort4 u;
    u.x = f2b(v.x); u.y = f2b(v.y); u.z = f2b(v.z); u.w = f2b(v.w);
    ((ushort4*)out)[i] = u;
  }
}

// ---------------- transpose + cast: W[K,N] fp32 -> WT[N,K] bf16 ------------
__global__ __launch_bounds__(256) void transpose_cast(
    const float* __restrict__ W, ushort* __restrict__ WT, int K, int N) {
  __shared__ ushort tile[32][33];
  const int tx = threadIdx.x & 31, ty = threadIdx.x >> 5;
  const int n0 = blockIdx.x * 32, k0 = blockIdx.y * 32;
#pragma unroll
  for (int i = 0; i < 4; ++i)
    tile[ty + i * 8][tx] = f2b(W[(size_t)(k0 + ty + i * 8) * N + n0 + tx]);
  __syncthreads();
#pragma unroll
  for (int i = 0; i < 4; ++i)
    WT[(size_t)(n0 + ty + i * 8) * K + k0 + tx] = tile[tx][ty + i * 8];
}

// ---------------- bf16 MFMA GEMM: C[M,N] = A[M,K] @ BT[N,K]^T --------------
template <bool BF16_OUT>
__global__ __launch_bounds__(256) void gemm_mfma(
    const ushort* __restrict__ A, const ushort* __restrict__ BT,
    void* __restrict__ Cv, int M, int N, int K) {
  __shared__ ushort As[128 * 64];
  __shared__ ushort Bs[128 * 64];
  const int t = threadIdx.x;
  const int w = t >> 6, lane = t & 63;
  const int m0 = blockIdx.y * 128, n0 = blockIdx.x * 128;
  const int srow = lane >> 3;
  const int scol = (lane & 7) * 8;
  const int wm = (w >> 1) * 64, wn = (w & 1) * 64;
  const int fr = lane & 15, kb = lane >> 4;
  f32x4 acc[4][4] = {};

  for (int k0 = 0; k0 < K; k0 += 64) {
#pragma unroll
    for (int i = 0; i < 4; ++i) {
      const int row = (i * 4 + w) * 8 + srow;
      gload16(&A[(size_t)(m0 + row) * K + k0 + scol], &As[row * 64 + scol]);
      gload16(&BT[(size_t)(n0 + row) * K + k0 + scol], &Bs[row * 64 + scol]);
    }
    __syncthreads();
#pragma unroll
    for (int ks = 0; ks < 2; ++ks) {
      const int ka = ks * 32 + kb * 8;
      short8 af[4], bfr[4];
#pragma unroll
      for (int mf = 0; mf < 4; ++mf)
        af[mf] = *(const short8*)&As[(wm + mf * 16 + fr) * 64 + ka];
#pragma unroll
      for (int nf = 0; nf < 4; ++nf)
        bfr[nf] = *(const short8*)&Bs[(wn + nf * 16 + fr) * 64 + ka];
#pragma unroll
      for (int mf = 0; mf < 4; ++mf)
#pragma unroll
        for (int nf = 0; nf < 4; ++nf)
          acc[mf][nf] = __builtin_amdgcn_mfma_f32_16x16x32_bf16(
              af[mf], bfr[nf], acc[mf][nf], 0, 0, 0);
    }
    __syncthreads();
  }
  const int orow = m0 + wm + (lane >> 4) * 4;
  const int ocol = n0 + wn + fr;
#pragma unroll
  for (int mf = 0; mf < 4; ++mf)
#pragma unroll
    for (int nf = 0; nf < 4; ++nf)
#pragma unroll
      for (int j = 0; j < 4; ++j) {
        const size_t off = (size_t)(orow + mf * 16 + j) * N + ocol + nf * 16;
        if constexpr (BF16_OUT)
          ((ushort*)Cv)[off] = f2b(acc[mf][nf][j]);
        else
          ((float*)Cv)[off] = acc[mf][nf][j];
      }
}

// ---------------- b/a projections + gates (g = log decay) ------------------
__global__ __launch_bounds__(256) void ba_kernel(
    const float* __restrict__ hs, const float* __restrict__ w_b,
    const float* __restrict__ w_a, const float* __restrict__ dt_bias,
    const float* __restrict__ A_log, float* __restrict__ gbuf,
    float* __restrict__ beta) {
  const int row = blockIdx.x;
  const int t = threadIdx.x;
  __shared__ float hsrow[HSZ];
  __shared__ float rb[256], ra[256];
  for (int c = t; c < HSZ; c += 256) hsrow[c] = hs[(size_t)row * HSZ + c];
  __syncthreads();
  const int h = t & 31, p = t >> 5;
  float sb = 0.f, sa = 0.f;
  const int kbeg = p * 256;
  for (int k = kbeg; k < kbeg + 256; ++k) {
    float x = hsrow[k];
    sb += x * w_b[k * NUM_V_HEADS + h];
    sa += x * w_a[k * NUM_V_HEADS + h];
  }
  rb[t] = sb;
  ra[t] = sa;
  __syncthreads();
  if (t < NUM_V_HEADS) {
    float b = 0.f, a = 0.f;
#pragma unroll
    for (int q = 0; q < 8; ++q) {
      b += rb[t + 32 * q];
      a += ra[t + 32 * q];
    }
    float bet = 1.f / (1.f + expf(-b));
    float x = a + dt_bias[t];
    float sp = (x > 20.f) ? x : log1pf(expf(x));
    gbuf[(size_t)row * NUM_V_HEADS + t] = -expf(A_log[t]) * sp;
    beta[(size_t)row * NUM_V_HEADS + t] = bet;
  }
}

// ---------------- causal conv + silu + l2norm (bf16) -----------------------
__global__ __launch_bounds__(256) void conv_kernel(
    const ushort* __restrict__ mixed, const float* __restrict__ conv_w,
    ushort* __restrict__ qkv) {
  const int row = blockIdx.x;
  const int s = row & (SSEQ - 1);
  const int t = threadIdx.x;
  __shared__ float buf[CONV_DIM];
  const ushort* mrow = mixed + (size_t)row * CONV_DIM;
  for (int c = t; c < CONV_DIM; c += 256) {
    float accv = 0.f;
#pragma unroll
    for (int j = 0; j < 4; ++j) {
      int ds = s - 3 + j;
      if (ds >= 0)
        accv += bfu(mrow[(ptrdiff_t)(ds - s) * CONV_DIM + c]) * conv_w[c * 4 + j];
    }
    buf[c] = accv / (1.f + expf(-accv));
  }
  __syncthreads();
  const int grp = t >> 3, r = t & 7;
  const float* gp = buf + grp * DKH + r * 16;
  float ssq = 0.f;
#pragma unroll
  for (int i = 0; i < 16; ++i) {
    float x = gp[i];
    ssq += x * x;
  }
  ssq += __shfl_xor(ssq, 1, 64);
  ssq += __shfl_xor(ssq, 2, 64);
  ssq += __shfl_xor(ssq, 4, 64);
  float sc = rsqrtf(ssq + 1e-6f);
  if (grp < 16) sc *= 0.08838834764831845f;
  ushort* orow = qkv + (size_t)row * CONV_DIM;
#pragma unroll
  for (int i = 0; i < 16; ++i) orow[grp * DKH + r * 16 + i] = f2b(gp[i] * sc);
  for (int c = 2 * KEY_DIM + t; c < CONV_DIM; c += 256) orow[c] = f2b(buf[c]);
}

// ---------------- chunked gated delta rule (WY form) -----------------------
// grid = 512: (b:2) x (h:32) x (dvq:8, DVB=16 v-cols). 256 thr, 2 blocks/CU.
__global__ __launch_bounds__(256, 2) void recur_chunk_kernel(
    const ushort* __restrict__ qkv, const float* __restrict__ gbuf,
    const float* __restrict__ beta, float* __restrict__ o) {
  const int bid = blockIdx.x;
  const int dvq = bid & 7;
  const int h = (bid >> 3) & 31;
  const int b = bid >> 8;
  const int hk = h >> 1;
  const int t = threadIdx.x;
  const int w = t >> 6, lane = t & 63;
  const int fr = lane & 15, fq = lane >> 4;

  __shared__ ushort Klds[64 * 128];    // 16 KB
  __shared__ ushort Qlds[64 * 128];    // 16 KB
  __shared__ ushort Vlds[64 * DVB];    // 2 KB
  __shared__ ushort Sth[DVB * 128];    // 4 KB  S0^T hi (bf16)
  __shared__ ushort Stl[DVB * 128];    // 4 KB  S0^T lo
  __shared__ float Alds[64 * ALD];     // 16.25 KB
  __shared__ float Ulds[64 * ULD];     // 4.25 KB
  __shared__ ushort UTs[DVB * 64];     // 2 KB  exp(G63-Gi)*u
  __shared__ ushort UTo[DVB * 64];     // 2 KB  plain u
  __shared__ ushort Wb[64 * 64];       // 8 KB
  __shared__ float Gs[64], Bsh[64];

  // S state in registers: sreg[dt][jj] = S[(w*2+dt)*16 + fq*4 + jj][fr]
  float sreg[2][4] = {};

  const int qcol = hk * DKH;
  const int kcol = KEY_DIM + hk * DKH;
  const int vcol = 2 * KEY_DIM + h * DVH + dvq * DVB;
  const int ocol = h * DVH + dvq * DVB;

  for (int c = 0; c < NCHUNK; ++c) {
    const int row0 = b * SSEQ + c * CHUNK;

    // ---- P1: load K/Q (swizzled) + V; gate scan; S -> Sth/Stl ------------
#pragma unroll
    for (int r = 0; r < 4; ++r) {
      int vi = t + 256 * r;
      int row = vi >> 4, gr = vi & 15;
      const size_t gb = (size_t)(row0 + row) * CONV_DIM;
      short8 kv = *(const short8*)&qkv[gb + kcol + gr * 8];
      short8 qv = *(const short8*)&qkv[gb + qcol + gr * 8];
      *(short8*)&Klds[row * 128 + ((gr ^ (row & 7)) << 3)] = kv;
      *(short8*)&Qlds[row * 128 + ((gr ^ (row & 7)) << 3)] = qv;
    }
    {
      int row = t >> 2, c0 = (t & 3) * 4;
      *(ushort4*)&Vlds[row * DVB + c0] =
          *(const ushort4*)&qkv[(size_t)(row0 + row) * CONV_DIM + vcol + c0];
    }
    if (t < 64) {
      float s = gbuf[(size_t)(row0 + t) * NUM_V_HEADS + h];
#pragma unroll
      for (int off = 1; off < 64; off <<= 1) {
        float p = __shfl_up(s, off, 64);
        if (lane >= off) s += p;
      }
      Gs[t] = s;
      Bsh[t] = beta[(size_t)(row0 + t) * NUM_V_HEADS + h];
    }
#pragma unroll
    for (int dt = 0; dt < 2; ++dt)
#pragma unroll
      for (int jj = 0; jj < 4; ++jj) {
        int d = (w * 2 + dt) * 16 + fq * 4 + jj;
        float f = sreg[dt][jj];
        ushort hi = f2b(f);
        int idx = kidx(fr, d);
        Sth[idx] = hi;
        Stl[idx] = f2b(f - bfu(hi));
      }
    __syncthreads();  // B1

    // ---- P2: kkt, qkt, K@S0, Q@S0; build A + RHS -------------------------
    f32x4 kkt[4] = {}, qkt[4] = {}, ks0 = {}, qs0 = {};
#pragma unroll
    for (int ks = 0; ks < 4; ++ks) {
      int d0 = ks * 32 + fq * 8;
      short8 xk = *(const short8*)&Klds[kidx(w * 16 + fr, d0)];
      short8 xq = *(const short8*)&Qlds[kidx(w * 16 + fr, d0)];
#pragma unroll
      for (int j = 0; j < 4; ++j) {
        short8 yk = *(const short8*)&Klds[kidx(j * 16 + fr, d0)];
        kkt[j] = __builtin_amdgcn_mfma_f32_16x16x32_bf16(xk, yk, kkt[j], 0, 0, 0);
        qkt[j] = __builtin_amdgcn_mfma_f32_16x16x32_bf16(xq, yk, qkt[j], 0, 0, 0);
      }
      short8 yh = *(const short8*)&Sth[kidx(fr, d0)];
      short8 yl = *(const short8*)&Stl[kidx(fr, d0)];
      ks0 = __builtin_amdgcn_mfma_f32_16x16x32_bf16(xk, yh, ks0, 0, 0, 0);
      ks0 = __builtin_amdgcn_mfma_f32_16x16x32_bf16(xk, yl, ks0, 0, 0, 0);
      qs0 = __builtin_amdgcn_mfma_f32_16x16x32_bf16(xq, yh, qs0, 0, 0, 0);
      qs0 = __builtin_amdgcn_mfma_f32_16x16x32_bf16(xq, yl, qs0, 0, 0, 0);
    }
    f32x4 oacc;
#pragma unroll
    for (int j = 0; j < 4; ++j)
#pragma unroll
      for (int jj = 0; jj < 4; ++jj) {
        int i = w * 16 + fq * 4 + jj;
        int jc = j * 16 + fr;
        Alds[i * ALD + jc] =
            (jc < i) ? Bsh[i] * __expf(Gs[i] - Gs[jc]) * kkt[j][jj] : 0.f;
      }
#pragma unroll
    for (int jj = 0; jj < 4; ++jj) {
      int i = w * 16 + fq * 4 + jj;
      float eg = __expf(Gs[i]);
      Ulds[i * ULD + fr] = Bsh[i] * (bfu(Vlds[i * DVB + fr]) - eg * ks0[jj]);
      oacc[jj] = qs0[jj] * eg;
    }
    __syncthreads();  // B2

    // ---- P3: wave 0 solves (I+A)U = RHS; waves 1-3 build Wb rows 16-63 ---
    if (w == 0) {
#pragma unroll
      for (int ib = 0; ib < 4; ++ib) {
        if (ib > 0) {
          const int cc = lane & 15, rr = lane >> 4;
          const int rbase = ib * 16 + rr * 4;
          float a0 = 0.f, a1 = 0.f, a2 = 0.f, a3 = 0.f;
#pragma unroll
          for (int j = 0; j < ib * 16; ++j) {
            float uj = Ulds[j * ULD + cc];
            a0 += Alds[(rbase + 0) * ALD + j] * uj;
            a1 += Alds[(rbase + 1) * ALD + j] * uj;
            a2 += Alds[(rbase + 2) * ALD + j] * uj;
            a3 += Alds[(rbase + 3) * ALD + j] * uj;
          }
          Ulds[(rbase + 0) * ULD + cc] -= a0;
          Ulds[(rbase + 1) * ULD + cc] -= a1;
          Ulds[(rbase + 2) * ULD + cc] -= a2;
          Ulds[(rbase + 3) * ULD + cc] -= a3;
          asm volatile("s_waitcnt lgkmcnt(0)" ::: "memory");
          __builtin_amdgcn_sched_barrier(0);
        }
        if (lane < 16) {
          float u[16];
#pragma unroll
          for (int i = 0; i < 16; ++i) u[i] = Ulds[(ib * 16 + i) * ULD + lane];
#pragma unroll
          for (int j = 0; j < 15; ++j) {
#pragma unroll
            for (int i = 0; i < 16; ++i)
              if (i > j) u[i] -= Alds[(ib * 16 + i) * ALD + ib * 16 + j] * u[j];
          }
#pragma unroll
          for (int i = 1; i < 16; ++i) Ulds[(ib * 16 + i) * ULD + lane] = u[i];
        }
        asm volatile("s_waitcnt lgkmcnt(0)" ::: "memory");
        __builtin_amdgcn_sched_barrier(0);
      }
    } else {
#pragma unroll
      for (int j = 0; j < 4; ++j)
#pragma unroll
        for (int jj = 0; jj < 4; ++jj) {
          int tt = w * 16 + fq * 4 + jj;
          int i = j * 16 + fr;
          float val = (i <= tt) ? __expf(Gs[tt] - Gs[i]) * qkt[j][jj] : 0.f;
          Wb[widx(tt, i)] = f2b(val);
        }
    }
    __syncthreads();  // B3

    // ---- P4: UT transposes (all); wave 0 builds Wb rows 0-15 -------------
    {
      int i = lane, v0 = w * 4;
      float sc = __expf(Gs[63] - Gs[i]);
#pragma unroll
      for (int e = 0; e < 4; ++e) {
        float u = Ulds[i * ULD + v0 + e];
        int idx = widx(v0 + e, i);
        UTs[idx] = f2b(u * sc);
        UTo[idx] = f2b(u);
      }
    }
    if (w == 0) {
#pragma unroll
      for (int j = 0; j < 4; ++j)
#pragma unroll
        for (int jj = 0; jj < 4; ++jj) {
          int tt = fq * 4 + jj;
          int i = j * 16 + fr;
          float val = (i <= tt) ? __expf(Gs[tt] - Gs[i]) * qkt[j][jj] : 0.f;
          Wb[widx(tt, i)] = f2b(val);
        }
    }
    __syncthreads();  // B4

    // ---- P5: O = Lt*(QS0) + W@U; store; S := eGC*S + K^T@Us --------------
#pragma unroll
    for (int ks = 0; ks < 2; ++ks) {
      int i0 = ks * 32 + fq * 8;
      int trow = w * 16 + fr;
      short8 xw = *(const short8*)&Wb[trow * 64 + (((i0 >> 3) ^ (trow & 7)) << 3)];
      short8 yu = *(const short8*)&UTo[fr * 64 + (((i0 >> 3) ^ (fr & 7)) << 3)];
      oacc = __builtin_amdgcn_mfma_f32_16x16x32_bf16(xw, yu, oacc, 0, 0, 0);
    }
#pragma unroll
    for (int jj = 0; jj < 4; ++jj) {
      int tt = w * 16 + fq * 4 + jj;
      o[(size_t)(row0 + tt) * VALUE_DIM + ocol + fr] = oacc[jj];
    }
    {
      float eGC = __expf(Gs[63]);
#pragma unroll
      for (int dt = 0; dt < 2; ++dt) {
        const int dk0 = (w * 2 + dt) * 16;
        f32x4 sacc;
#pragma unroll
        for (int jj = 0; jj < 4; ++jj) sacc[jj] = sreg[dt][jj] * eGC;
        const int dkr = dk0 + fr;
#pragma unroll
        for (int ks = 0; ks < 2; ++ks) {
          short8 xk;
#pragma unroll
          for (int e = 0; e < 8; ++e)
            xk[e] = (short)Klds[kidx(ks * 32 + fq * 8 + e, dkr)];
          int i0 = ks * 32 + fq * 8;
          short8 yu = *(const short8*)&UTs[fr * 64 + (((i0 >> 3) ^ (fr & 7)) << 3)];
          sacc = __builtin_amdgcn_mfma_f32_16x16x32_bf16(xk, yu, sacc, 0, 0, 0);
        }
#pragma unroll
        for (int jj = 0; jj < 4; ++jj) sreg[dt][jj] = sacc[jj];
      }
    }
    __syncthreads();  // B5 (protects Klds/Sth for next chunk's P1)
  }
}

// ---------------- gated RMSNorm -> bf16 ------------------------------------
__global__ __launch_bounds__(256) void gnorm_kernel(
    const float* __restrict__ o, const ushort* __restrict__ z,
    const float* __restrict__ gamma, ushort* __restrict__ ob) {
  const int row = blockIdx.x;
  const int t = threadIdx.x;
  const int grp = t >> 3, r = t & 7;
  const float* op = o + (size_t)row * VALUE_DIM + grp * DVH + r * 16;
  const ushort* zp = z + (size_t)row * VALUE_DIM + grp * DVH + r * 16;
  ushort* obp = ob + (size_t)row * VALUE_DIM + grp * DVH + r * 16;
  float vals[16];
  float ssq = 0.f;
#pragma unroll
  for (int i = 0; i < 16; ++i) {
    float zz = bfu(zp[i]);
    float x = op[i] * (zz / (1.f + expf(-zz)));
    vals[i] = x;
    ssq += x * x;
  }
  ssq += __shfl_xor(ssq, 1, 64);
  ssq += __shfl_xor(ssq, 2, 64);
  ssq += __shfl_xor(ssq, 4, 64);
  float sc = rsqrtf(ssq * (1.f / 128.f) + 1e-6f);
#pragma unroll
  for (int i = 0; i < 16; ++i) obp[i] = f2b(vals[i] * sc * gamma[r * 16 + i]);
}

// ---------------------------------------------------------------------------
extern "C" void kernel_launch(void* const* d_in, const int* in_sizes, int n_in,
                              void* d_out, int out_size, void* d_ws,
                              size_t ws_size, hipStream_t stream) {
  const float* hs = (const float*)d_in[0];
  const float* w_qkv = (const float*)d_in[1];
  const float* w_z = (const float*)d_in[2];
  const float* w_b = (const float*)d_in[3];
  const float* w_a = (const float*)d_in[4];
  const float* conv_w = (const float*)d_in[5];
  const float* dt_bias = (const float*)d_in[6];
  const float* A_log = (const float*)d_in[7];
  const float* gamma = (const float*)d_in[8];
  const float* w_out = (const float*)d_in[9];
  float* out = (float*)d_out;
  char* wsb = (char*)d_ws;

  // workspace layout (241 MiB total)
  ushort* hs_b = (ushort*)wsb;                      // 16 MiB
  ushort* wqkvT = hs_b + (size_t)MM * HSZ;          // 32 MiB
  ushort* wzT = wqkvT + (size_t)CONV_DIM * HSZ;     // 16 MiB
  ushort* woutT = wzT + (size_t)VALUE_DIM * HSZ;    // 16 MiB
  ushort* mixed = woutT + (size_t)HSZ * VALUE_DIM;  // 64 MiB bf16
  ushort* qkv = mixed + (size_t)MM * CONV_DIM;      // 64 MiB bf16
  ushort* z = qkv + (size_t)MM * CONV_DIM;          // 32 MiB bf16
  float* gbuf = (float*)(z + (size_t)MM * VALUE_DIM);
  float* beta = gbuf + (size_t)MM * NUM_V_HEADS;
  float* o = (float*)mixed;  // fp32, aliases retired mixed (64 MiB)
  ushort* ob = qkv;          // bf16, aliases retired qkv

  cast_bf16_kernel<<<(MM * HSZ / 4 + 255) / 256, 256, 0, stream>>>(
      hs, hs_b, MM * HSZ / 4);
  transpose_cast<<<dim3(CONV_DIM / 32, HSZ / 32), 256, 0, stream>>>(
      w_qkv, wqkvT, HSZ, CONV_DIM);
  transpose_cast<<<dim3(VALUE_DIM / 32, HSZ / 32), 256, 0, stream>>>(
      w_z, wzT, HSZ, VALUE_DIM);
  transpose_cast<<<dim3(HSZ / 32, VALUE_DIM / 32), 256, 0, stream>>>(
      w_out, woutT, VALUE_DIM, HSZ);

  gemm_mfma<true><<<dim3(CONV_DIM / 128, MM / 128), 256, 0, stream>>>(
      hs_b, wqkvT, mixed, MM, CONV_DIM, HSZ);
  gemm_mfma<true><<<dim3(VALUE_DIM / 128, MM / 128), 256, 0, stream>>>(
      hs_b, wzT, z, MM, VALUE_DIM, HSZ);
  ba_kernel<<<MM, 256, 0, stream>>>(hs, w_b, w_a, dt_bias, A_log, gbuf, beta);
  conv_kernel<<<MM, 256, 0, stream>>>(mixed, conv_w, qkv);
  recur_chunk_kernel<<<512, 256, 0, stream>>>(qkv, gbuf, beta, o);
  gnorm_kernel<<<MM, 256, 0, stream>>>(o, z, gamma, ob);
  gemm_mfma<false><<<dim3(HSZ / 128, MM / 128), 256, 0, stream>>>(
      ob, woutT, out, MM, HSZ, VALUE_DIM);
}

// Round 7
// 998.580 us; speedup vs baseline: 1.3108x; 1.2065x over previous
//
#include <hip/hip_runtime.h>
#include <hip/hip_bf16.h>
#include <cstdint>

// ---------------------------------------------------------------------------
// Qwen3.5 GatedDeltaNet — round 7: two-stage chunked delta rule.
//  Stage 1 (chunk_T_kernel, 2048-way parallel): T = (I+A)^{-1} per
//    (b,h,chunk); in-register column solve; T stored bf16 (16 MiB, reuses
//    retired hs_b region).
//  Stage 2 (recur_chunk_kernel): sequential chunk loop with NO solve —
//    U = T@RHS via MFMA; 4 barriers/chunk; ~48.5 KB LDS; Q direct-to-reg.
//  GEMMs/conv/norm unchanged from round 6.
// ---------------------------------------------------------------------------

#define HSZ 2048
#define NUM_K_HEADS 16
#define NUM_V_HEADS 32
#define DKH 128
#define DVH 128
#define KEY_DIM 2048
#define VALUE_DIM 4096
#define CONV_DIM 8192
#define BB 2
#define SSEQ 2048
#define MM (BB * SSEQ) /* 4096 rows */
#define CHUNK 64
#define NCHUNK (SSEQ / CHUNK) /* 32 */
#define DVB 16 /* v-cols per recur block */

typedef __hip_bfloat16 bf16;
typedef short short8 __attribute__((ext_vector_type(8)));
typedef float f32x4 __attribute__((ext_vector_type(4)));

__device__ __forceinline__ float bfu(ushort u) {
  union { float f; uint32_t i; } x;
  x.i = ((uint32_t)u) << 16;
  return x.f;
}
__device__ __forceinline__ ushort f2b(float f) {
  bf16 h = __float2bfloat16(f);
  return *reinterpret_cast<ushort*>(&h);
}

__device__ __forceinline__ void gload16(const void* g, const void* l) {
  __builtin_amdgcn_global_load_lds(
      (const __attribute__((address_space(1))) unsigned int*)g,
      (__attribute__((address_space(3))) unsigned int*)(const_cast<void*>(l)),
      16, 0, 0);
}

// swizzled LDS indexers (break D=128/D=64 row-major bank pathology)
__device__ __forceinline__ int kidx(int r, int d) {  // [*][128] bf16
  return r * 128 + (((d >> 3) ^ (r & 7)) << 3) + (d & 7);
}
__device__ __forceinline__ int widx(int r, int d) {  // [*][64] bf16
  return r * 64 + (((d >> 3) ^ (r & 7)) << 3) + (d & 7);
}

// ---------------- cast fp32 -> bf16 ----------------------------------------
__global__ __launch_bounds__(256) void cast_bf16_kernel(
    const float* __restrict__ in, ushort* __restrict__ out, int n4) {
  int i = blockIdx.x * 256 + threadIdx.x;
  if (i < n4) {
    float4 v = ((const float4*)in)[i];
    ushort4 u;
    u.x = f2b(v.x); u.y = f2b(v.y); u.z = f2b(v.z); u.w = f2b(v.w);
    ((ushort4*)out)[i] = u;
  }
}

// ---------------- transpose + cast: W[K,N] fp32 -> WT[N,K] bf16 ------------
__global__ __launch_bounds__(256) void transpose_cast(
    const float* __restrict__ W, ushort* __restrict__ WT, int K, int N) {
  __shared__ ushort tile[32][33];
  const int tx = threadIdx.x & 31, ty = threadIdx.x >> 5;
  const int n0 = blockIdx.x * 32, k0 = blockIdx.y * 32;
#pragma unroll
  for (int i = 0; i < 4; ++i)
    tile[ty + i * 8][tx] = f2b(W[(size_t)(k0 + ty + i * 8) * N + n0 + tx]);
  __syncthreads();
#pragma unroll
  for (int i = 0; i < 4; ++i)
    WT[(size_t)(n0 + ty + i * 8) * K + k0 + tx] = tile[tx][ty + i * 8];
}

// ---------------- bf16 MFMA GEMM: C[M,N] = A[M,K] @ BT[N,K]^T --------------
template <bool BF16_OUT>
__global__ __launch_bounds__(256) void gemm_mfma(
    const ushort* __restrict__ A, const ushort* __restrict__ BT,
    void* __restrict__ Cv, int M, int N, int K) {
  __shared__ ushort As[128 * 64];
  __shared__ ushort Bs[128 * 64];
  const int t = threadIdx.x;
  const int w = t >> 6, lane = t & 63;
  const int m0 = blockIdx.y * 128, n0 = blockIdx.x * 128;
  const int srow = lane >> 3;
  const int scol = (lane & 7) * 8;
  const int wm = (w >> 1) * 64, wn = (w & 1) * 64;
  const int fr = lane & 15, kb = lane >> 4;
  f32x4 acc[4][4] = {};

  for (int k0 = 0; k0 < K; k0 += 64) {
#pragma unroll
    for (int i = 0; i < 4; ++i) {
      const int row = (i * 4 + w) * 8 + srow;
      gload16(&A[(size_t)(m0 + row) * K + k0 + scol], &As[row * 64 + scol]);
      gload16(&BT[(size_t)(n0 + row) * K + k0 + scol], &Bs[row * 64 + scol]);
    }
    __syncthreads();
#pragma unroll
    for (int ks = 0; ks < 2; ++ks) {
      const int ka = ks * 32 + kb * 8;
      short8 af[4], bfr[4];
#pragma unroll
      for (int mf = 0; mf < 4; ++mf)
        af[mf] = *(const short8*)&As[(wm + mf * 16 + fr) * 64 + ka];
#pragma unroll
      for (int nf = 0; nf < 4; ++nf)
        bfr[nf] = *(const short8*)&Bs[(wn + nf * 16 + fr) * 64 + ka];
#pragma unroll
      for (int mf = 0; mf < 4; ++mf)
#pragma unroll
        for (int nf = 0; nf < 4; ++nf)
          acc[mf][nf] = __builtin_amdgcn_mfma_f32_16x16x32_bf16(
              af[mf], bfr[nf], acc[mf][nf], 0, 0, 0);
    }
    __syncthreads();
  }
  const int orow = m0 + wm + (lane >> 4) * 4;
  const int ocol = n0 + wn + fr;
#pragma unroll
  for (int mf = 0; mf < 4; ++mf)
#pragma unroll
    for (int nf = 0; nf < 4; ++nf)
#pragma unroll
      for (int j = 0; j < 4; ++j) {
        const size_t off = (size_t)(orow + mf * 16 + j) * N + ocol + nf * 16;
        if constexpr (BF16_OUT)
          ((ushort*)Cv)[off] = f2b(acc[mf][nf][j]);
        else
          ((float*)Cv)[off] = acc[mf][nf][j];
      }
}

// ---------------- b/a projections + gates (g = log decay) ------------------
__global__ __launch_bounds__(256) void ba_kernel(
    const float* __restrict__ hs, const float* __restrict__ w_b,
    const float* __restrict__ w_a, const float* __restrict__ dt_bias,
    const float* __restrict__ A_log, float* __restrict__ gbuf,
    float* __restrict__ beta) {
  const int row = blockIdx.x;
  const int t = threadIdx.x;
  __shared__ float hsrow[HSZ];
  __shared__ float rb[256], ra[256];
  for (int c = t; c < HSZ; c += 256) hsrow[c] = hs[(size_t)row * HSZ + c];
  __syncthreads();
  const int h = t & 31, p = t >> 5;
  float sb = 0.f, sa = 0.f;
  const int kbeg = p * 256;
  for (int k = kbeg; k < kbeg + 256; ++k) {
    float x = hsrow[k];
    sb += x * w_b[k * NUM_V_HEADS + h];
    sa += x * w_a[k * NUM_V_HEADS + h];
  }
  rb[t] = sb;
  ra[t] = sa;
  __syncthreads();
  if (t < NUM_V_HEADS) {
    float b = 0.f, a = 0.f;
#pragma unroll
    for (int q = 0; q < 8; ++q) {
      b += rb[t + 32 * q];
      a += ra[t + 32 * q];
    }
    float bet = 1.f / (1.f + expf(-b));
    float x = a + dt_bias[t];
    float sp = (x > 20.f) ? x : log1pf(expf(x));
    gbuf[(size_t)row * NUM_V_HEADS + t] = -expf(A_log[t]) * sp;
    beta[(size_t)row * NUM_V_HEADS + t] = bet;
  }
}

// ---------------- causal conv + silu + l2norm (bf16) -----------------------
__global__ __launch_bounds__(256) void conv_kernel(
    const ushort* __restrict__ mixed, const float* __restrict__ conv_w,
    ushort* __restrict__ qkv) {
  const int row = blockIdx.x;
  const int s = row & (SSEQ - 1);
  const int t = threadIdx.x;
  __shared__ float buf[CONV_DIM];
  const ushort* mrow = mixed + (size_t)row * CONV_DIM;
  for (int c = t; c < CONV_DIM; c += 256) {
    float accv = 0.f;
#pragma unroll
    for (int j = 0; j < 4; ++j) {
      int ds = s - 3 + j;
      if (ds >= 0)
        accv += bfu(mrow[(ptrdiff_t)(ds - s) * CONV_DIM + c]) * conv_w[c * 4 + j];
    }
    buf[c] = accv / (1.f + expf(-accv));
  }
  __syncthreads();
  const int grp = t >> 3, r = t & 7;
  const float* gp = buf + grp * DKH + r * 16;
  float ssq = 0.f;
#pragma unroll
  for (int i = 0; i < 16; ++i) {
    float x = gp[i];
    ssq += x * x;
  }
  ssq += __shfl_xor(ssq, 1, 64);
  ssq += __shfl_xor(ssq, 2, 64);
  ssq += __shfl_xor(ssq, 4, 64);
  float sc = rsqrtf(ssq + 1e-6f);
  if (grp < 16) sc *= 0.08838834764831845f;
  ushort* orow = qkv + (size_t)row * CONV_DIM;
#pragma unroll
  for (int i = 0; i < 16; ++i) orow[grp * DKH + r * 16 + i] = f2b(gp[i] * sc);
  for (int c = 2 * KEY_DIM + t; c < CONV_DIM; c += 256) orow[c] = f2b(buf[c]);
}

// ---------------- stage 1: per-chunk T = (I+A)^{-1}, bf16 ------------------
// grid = 2048: c = bid&31, h = (bid>>5)&31, b = bid>>10. 256 thr.
__global__ __launch_bounds__(256) void chunk_T_kernel(
    const ushort* __restrict__ qkv, const float* __restrict__ gbuf,
    const float* __restrict__ beta, ushort* __restrict__ Tbuf) {
  const int bid = blockIdx.x;
  const int c = bid & 31;
  const int h = (bid >> 5) & 31;
  const int b = bid >> 10;
  const int hk = h >> 1;
  const int t = threadIdx.x;
  const int w = t >> 6, lane = t & 63;
  const int fr = lane & 15, fq = lane >> 4;

  __shared__ ushort Klds[64 * 128];          // 16 KB
  __shared__ __align__(16) float AT[64][68]; // 17.4 KB, AT[j][i] = A[i][j]
  __shared__ float Gs[64], Bsh[64];

  const int row0 = b * SSEQ + c * CHUNK;
  const int kcol = KEY_DIM + hk * DKH;

#pragma unroll
  for (int r = 0; r < 4; ++r) {
    int vi = t + 256 * r;
    int row = vi >> 4, gr = vi & 15;
    *(short8*)&Klds[row * 128 + ((gr ^ (row & 7)) << 3)] =
        *(const short8*)&qkv[(size_t)(row0 + row) * CONV_DIM + kcol + gr * 8];
  }
  if (t < 64) {
    float s = gbuf[(size_t)(row0 + t) * NUM_V_HEADS + h];
#pragma unroll
    for (int off = 1; off < 64; off <<= 1) {
      float p = __shfl_up(s, off, 64);
      if (lane >= off) s += p;
    }
    Gs[t] = s;
    Bsh[t] = beta[(size_t)(row0 + t) * NUM_V_HEADS + h];
  }
  __syncthreads();

  // KK^T -> AT (fp32)
  f32x4 kkt[4] = {};
#pragma unroll
  for (int ks = 0; ks < 4; ++ks) {
    int d0 = ks * 32 + fq * 8;
    short8 xk = *(const short8*)&Klds[kidx(w * 16 + fr, d0)];
#pragma unroll
    for (int j = 0; j < 4; ++j) {
      short8 yk = *(const short8*)&Klds[kidx(j * 16 + fr, d0)];
      kkt[j] = __builtin_amdgcn_mfma_f32_16x16x32_bf16(xk, yk, kkt[j], 0, 0, 0);
    }
  }
#pragma unroll
  for (int j = 0; j < 4; ++j)
#pragma unroll
    for (int jj = 0; jj < 4; ++jj) {
      int i = w * 16 + fq * 4 + jj;
      int jc = j * 16 + fr;
      AT[jc][i] = (jc < i) ? Bsh[i] * __expf(Gs[i] - Gs[jc]) * kkt[j][jj] : 0.f;
    }
  __syncthreads();

  // wave 0: in-register forward substitution, lane = column of T
  if (w == 0) {
    float u[64];
#pragma unroll
    for (int i = 0; i < 64; ++i) u[i] = (i == lane) ? 1.f : 0.f;
#pragma unroll
    for (int j = 0; j < 63; ++j) {
      float xj = u[j];
      const int i0 = (j + 1) & ~3;
#pragma unroll
      for (int ii = i0; ii < 64; ii += 4) {
        float4 a4 = *(const float4*)&AT[j][ii];  // broadcast, aligned
        if (ii + 0 > j) u[ii + 0] -= a4.x * xj;
        if (ii + 1 > j) u[ii + 1] -= a4.y * xj;
        if (ii + 2 > j) u[ii + 2] -= a4.z * xj;
        if (ii + 3 > j) u[ii + 3] -= a4.w * xj;
      }
    }
    ushort* Tg = Tbuf + (size_t)bid * 4096;
#pragma unroll
    for (int i = 0; i < 64; ++i) Tg[i * 64 + lane] = f2b(u[i]);  // coalesced
  }
}

// ---------------- stage 2: sequential chunk loop (no solve) ----------------
// grid = 512: (b:2) x (h:32) x (dvq:8, DVB=16). 256 thr, 2 blocks/CU.
__global__ __launch_bounds__(256, 2) void recur_chunk_kernel(
    const ushort* __restrict__ qkv, const float* __restrict__ gbuf,
    const float* __restrict__ beta, const ushort* __restrict__ Tbuf,
    float* __restrict__ o) {
  const int bid = blockIdx.x;
  const int dvq = bid & 7;
  const int h = (bid >> 3) & 31;
  const int b = bid >> 8;
  const int hk = h >> 1;
  const int t = threadIdx.x;
  const int w = t >> 6, lane = t & 63;
  const int fr = lane & 15, fq = lane >> 4;

  __shared__ ushort Klds[64 * 128];  // 16 KB
  __shared__ ushort Vlds[64 * DVB];  // 2 KB
  __shared__ ushort Sth[DVB * 128];  // 4 KB  S0^T hi
  __shared__ ushort Stl[DVB * 128];  // 4 KB  S0^T lo
  __shared__ ushort Th[64 * 64];     // 8 KB  T (widx)
  __shared__ ushort Ut[DVB * 64];    // 2 KB  RHS^T (widx)
  __shared__ ushort UTs[DVB * 64];   // 2 KB  exp(G63-Gi)*u
  __shared__ ushort UTo[DVB * 64];   // 2 KB  plain u
  __shared__ ushort Wb[64 * 64];     // 8 KB
  __shared__ float Gs[64], Bsh[64];

  float sreg[2][4] = {};  // S[(w*2+dt)*16 + fq*4 + jj][fr]

  const int qcol = hk * DKH;
  const int kcol = KEY_DIM + hk * DKH;
  const int vcol = 2 * KEY_DIM + h * DVH + dvq * DVB;
  const int ocol = h * DVH + dvq * DVB;
  const size_t tbase0 = ((size_t)(b * 32 + h) * 32) * 4096;

  for (int c = 0; c < NCHUNK; ++c) {
    const int row0 = b * SSEQ + c * CHUNK;

    // ---- P1: Q->regs, T->regs, K/V->LDS, gates, S->hi/lo, T->Th ----------
    short8 xq[4];
#pragma unroll
    for (int ks = 0; ks < 4; ++ks)
      xq[ks] = *(const short8*)&qkv[(size_t)(row0 + w * 16 + fr) * CONV_DIM +
                                    qcol + ks * 32 + fq * 8];
    const ushort* Tg = Tbuf + tbase0 + (size_t)c * 4096;
    short8 tv0 = *(const short8*)&Tg[t * 16];
    short8 tv1 = *(const short8*)&Tg[t * 16 + 8];
#pragma unroll
    for (int r = 0; r < 4; ++r) {
      int vi = t + 256 * r;
      int row = vi >> 4, gr = vi & 15;
      *(short8*)&Klds[row * 128 + ((gr ^ (row & 7)) << 3)] =
          *(const short8*)&qkv[(size_t)(row0 + row) * CONV_DIM + kcol + gr * 8];
    }
    if (t < 128) {
      int row = t >> 1, c0 = (t & 1) * 8;
      *(short8*)&Vlds[row * DVB + c0] =
          *(const short8*)&qkv[(size_t)(row0 + row) * CONV_DIM + vcol + c0];
    }
    if (t < 64) {
      float s = gbuf[(size_t)(row0 + t) * NUM_V_HEADS + h];
#pragma unroll
      for (int off = 1; off < 64; off <<= 1) {
        float p = __shfl_up(s, off, 64);
        if (lane >= off) s += p;
      }
      Gs[t] = s;
      Bsh[t] = beta[(size_t)(row0 + t) * NUM_V_HEADS + h];
    }
#pragma unroll
    for (int dt = 0; dt < 2; ++dt)
#pragma unroll
      for (int jj = 0; jj < 4; ++jj) {
        int d = (w * 2 + dt) * 16 + fq * 4 + jj;
        float f = sreg[dt][jj];
        ushort hi = f2b(f);
        int idx = kidx(fr, d);
        Sth[idx] = hi;
        Stl[idx] = f2b(f - bfu(hi));
      }
    {
      int r = t >> 2, d0 = (t & 3) * 16;
      *(short8*)&Th[widx(r, d0)] = tv0;
      *(short8*)&Th[widx(r, d0 + 8)] = tv1;
    }
    __syncthreads();  // B1

    // ---- P2: qkt, ks0, qs0; Wb; RHS -> Ut; oacc init ---------------------
    f32x4 qkt[4] = {}, ks0 = {}, qs0 = {};
#pragma unroll
    for (int ks = 0; ks < 4; ++ks) {
      int d0 = ks * 32 + fq * 8;
      short8 xk = *(const short8*)&Klds[kidx(w * 16 + fr, d0)];
#pragma unroll
      for (int j = 0; j < 4; ++j) {
        short8 yk = *(const short8*)&Klds[kidx(j * 16 + fr, d0)];
        qkt[j] = __builtin_amdgcn_mfma_f32_16x16x32_bf16(xq[ks], yk, qkt[j], 0, 0, 0);
      }
      short8 yh = *(const short8*)&Sth[kidx(fr, d0)];
      short8 yl = *(const short8*)&Stl[kidx(fr, d0)];
      ks0 = __builtin_amdgcn_mfma_f32_16x16x32_bf16(xk, yh, ks0, 0, 0, 0);
      ks0 = __builtin_amdgcn_mfma_f32_16x16x32_bf16(xk, yl, ks0, 0, 0, 0);
      qs0 = __builtin_amdgcn_mfma_f32_16x16x32_bf16(xq[ks], yh, qs0, 0, 0, 0);
      qs0 = __builtin_amdgcn_mfma_f32_16x16x32_bf16(xq[ks], yl, qs0, 0, 0, 0);
    }
#pragma unroll
    for (int j = 0; j < 4; ++j)
#pragma unroll
      for (int jj = 0; jj < 4; ++jj) {
        int tt = w * 16 + fq * 4 + jj;
        int i = j * 16 + fr;
        float val = (i <= tt) ? __expf(Gs[tt] - Gs[i]) * qkt[j][jj] : 0.f;
        Wb[widx(tt, i)] = f2b(val);
      }
    f32x4 oacc;
#pragma unroll
    for (int jj = 0; jj < 4; ++jj) {
      int i = w * 16 + fq * 4 + jj;
      float eg = __expf(Gs[i]);
      float rhs = Bsh[i] * (bfu(Vlds[i * DVB + fr]) - eg * ks0[jj]);
      Ut[widx(fr, i)] = f2b(rhs);
      oacc[jj] = qs0[jj] * eg;
    }
    __syncthreads();  // B2

    // ---- P3: U = Th @ Ut (MFMA); write UTo / UTs -------------------------
    {
      f32x4 uacc = {};
#pragma unroll
      for (int ks = 0; ks < 2; ++ks) {
        int j0 = ks * 32 + fq * 8;
        short8 ta = *(const short8*)&Th[widx(w * 16 + fr, j0)];
        short8 ub = *(const short8*)&Ut[widx(fr, j0)];
        uacc = __builtin_amdgcn_mfma_f32_16x16x32_bf16(ta, ub, uacc, 0, 0, 0);
      }
#pragma unroll
      for (int jj = 0; jj < 4; ++jj) {
        int i = w * 16 + fq * 4 + jj;
        float u = uacc[jj];
        UTo[widx(fr, i)] = f2b(u);
        UTs[widx(fr, i)] = f2b(u * __expf(Gs[63] - Gs[i]));
      }
    }
    __syncthreads();  // B3

    // ---- P4: O = oacc + Wb@U; store; S := e^G63 S + K^T @ Us -------------
#pragma unroll
    for (int ks = 0; ks < 2; ++ks) {
      int i0 = ks * 32 + fq * 8;
      short8 xw = *(const short8*)&Wb[widx(w * 16 + fr, i0)];
      short8 yu = *(const short8*)&UTo[widx(fr, i0)];
      oacc = __builtin_amdgcn_mfma_f32_16x16x32_bf16(xw, yu, oacc, 0, 0, 0);
    }
#pragma unroll
    for (int jj = 0; jj < 4; ++jj) {
      int tt = w * 16 + fq * 4 + jj;
      o[(size_t)(row0 + tt) * VALUE_DIM + ocol + fr] = oacc[jj];
    }
    {
      float eGC = __expf(Gs[63]);
#pragma unroll
      for (int dt = 0; dt < 2; ++dt) {
        const int dk0 = (w * 2 + dt) * 16;
        f32x4 sacc;
#pragma unroll
        for (int jj = 0; jj < 4; ++jj) sacc[jj] = sreg[dt][jj] * eGC;
        const int dkr = dk0 + fr;
#pragma unroll
        for (int ks = 0; ks < 2; ++ks) {
          short8 xk;
#pragma unroll
          for (int e = 0; e < 8; ++e)
            xk[e] = (short)Klds[kidx(ks * 32 + fq * 8 + e, dkr)];
          short8 yu = *(const short8*)&UTs[widx(fr, ks * 32 + fq * 8)];
          sacc = __builtin_amdgcn_mfma_f32_16x16x32_bf16(xk, yu, sacc, 0, 0, 0);
        }
#pragma unroll
        for (int jj = 0; jj < 4; ++jj) sreg[dt][jj] = sacc[jj];
      }
    }
    __syncthreads();  // B4 (protect LDS for next chunk's P1)
  }
}

// ---------------- gated RMSNorm -> bf16 ------------------------------------
__global__ __launch_bounds__(256) void gnorm_kernel(
    const float* __restrict__ o, const ushort* __restrict__ z,
    const float* __restrict__ gamma, ushort* __restrict__ ob) {
  const int row = blockIdx.x;
  const int t = threadIdx.x;
  const int grp = t >> 3, r = t & 7;
  const float* op = o + (size_t)row * VALUE_DIM + grp * DVH + r * 16;
  const ushort* zp = z + (size_t)row * VALUE_DIM + grp * DVH + r * 16;
  ushort* obp = ob + (size_t)row * VALUE_DIM + grp * DVH + r * 16;
  float vals[16];
  float ssq = 0.f;
#pragma unroll
  for (int i = 0; i < 16; ++i) {
    float zz = bfu(zp[i]);
    float x = op[i] * (zz / (1.f + expf(-zz)));
    vals[i] = x;
    ssq += x * x;
  }
  ssq += __shfl_xor(ssq, 1, 64);
  ssq += __shfl_xor(ssq, 2, 64);
  ssq += __shfl_xor(ssq, 4, 64);
  float sc = rsqrtf(ssq * (1.f / 128.f) + 1e-6f);
#pragma unroll
  for (int i = 0; i < 16; ++i) obp[i] = f2b(vals[i] * sc * gamma[r * 16 + i]);
}

// ---------------------------------------------------------------------------
extern "C" void kernel_launch(void* const* d_in, const int* in_sizes, int n_in,
                              void* d_out, int out_size, void* d_ws,
                              size_t ws_size, hipStream_t stream) {
  const float* hs = (const float*)d_in[0];
  const float* w_qkv = (const float*)d_in[1];
  const float* w_z = (const float*)d_in[2];
  const float* w_b = (const float*)d_in[3];
  const float* w_a = (const float*)d_in[4];
  const float* conv_w = (const float*)d_in[5];
  const float* dt_bias = (const float*)d_in[6];
  const float* A_log = (const float*)d_in[7];
  const float* gamma = (const float*)d_in[8];
  const float* w_out = (const float*)d_in[9];
  float* out = (float*)d_out;
  char* wsb = (char*)d_ws;

  // workspace layout (241 MiB total)
  ushort* hs_b = (ushort*)wsb;                      // 16 MiB (later: Tbuf)
  ushort* wqkvT = hs_b + (size_t)MM * HSZ;          // 32 MiB
  ushort* wzT = wqkvT + (size_t)CONV_DIM * HSZ;     // 16 MiB
  ushort* woutT = wzT + (size_t)VALUE_DIM * HSZ;    // 16 MiB
  ushort* mixed = woutT + (size_t)HSZ * VALUE_DIM;  // 64 MiB bf16
  ushort* qkv = mixed + (size_t)MM * CONV_DIM;      // 64 MiB bf16
  ushort* z = qkv + (size_t)MM * CONV_DIM;          // 32 MiB bf16
  float* gbuf = (float*)(z + (size_t)MM * VALUE_DIM);
  float* beta = gbuf + (size_t)MM * NUM_V_HEADS;
  float* o = (float*)mixed;   // fp32, aliases retired mixed (64 MiB)
  ushort* ob = qkv;           // bf16, aliases retired qkv
  ushort* Tbuf = hs_b;        // 2048 x 64 x 64 bf16 = 16 MiB, aliases retired hs_b

  cast_bf16_kernel<<<(MM * HSZ / 4 + 255) / 256, 256, 0, stream>>>(
      hs, hs_b, MM * HSZ / 4);
  transpose_cast<<<dim3(CONV_DIM / 32, HSZ / 32), 256, 0, stream>>>(
      w_qkv, wqkvT, HSZ, CONV_DIM);
  transpose_cast<<<dim3(VALUE_DIM / 32, HSZ / 32), 256, 0, stream>>>(
      w_z, wzT, HSZ, VALUE_DIM);
  transpose_cast<<<dim3(HSZ / 32, VALUE_DIM / 32), 256, 0, stream>>>(
      w_out, woutT, VALUE_DIM, HSZ);

  gemm_mfma<true><<<dim3(CONV_DIM / 128, MM / 128), 256, 0, stream>>>(
      hs_b, wqkvT, mixed, MM, CONV_DIM, HSZ);
  gemm_mfma<true><<<dim3(VALUE_DIM / 128, MM / 128), 256, 0, stream>>>(
      hs_b, wzT, z, MM, VALUE_DIM, HSZ);
  ba_kernel<<<MM, 256, 0, stream>>>(hs, w_b, w_a, dt_bias, A_log, gbuf, beta);
  conv_kernel<<<MM, 256, 0, stream>>>(mixed, conv_w, qkv);
  chunk_T_kernel<<<2048, 256, 0, stream>>>(qkv, gbuf, beta, Tbuf);  // hs_b dead
  recur_chunk_kernel<<<512, 256, 0, stream>>>(qkv, gbuf, beta, Tbuf, o);
  gnorm_kernel<<<MM, 256, 0, stream>>>(o, z, gamma, ob);
  gemm_mfma<false><<<dim3(HSZ / 128, MM / 128), 256, 0, stream>>>(
      ob, woutT, out, MM, HSZ, VALUE_DIM);
}

// Round 9
// 982.075 us; speedup vs baseline: 1.3328x; 1.0168x over previous
//
#include <hip/hip_runtime.h>
#include <hip/hip_bf16.h>
#include <cstdint>

// ---------------------------------------------------------------------------
// Qwen3.5 GatedDeltaNet — round 9: round-8 plan with the epilogue store bug
// fixed (it covered only 64 of 128 columns; now 8 iterations cover all).
//  * gemm_mfma: XCD-swizzle + LDS-staged coalesced bf16 epilogue
//  * chunk_T_kernel also precomputes W = mask(e^{dG} QK^T) (16 MiB bf16)
//  * recur_chunk_kernel: no QK^T / W-build (loads W flat), P2 halved
//  * ba_kernel: 8 rows/block (weight traffic /8)
// ---------------------------------------------------------------------------

#define HSZ 2048
#define NUM_K_HEADS 16
#define NUM_V_HEADS 32
#define DKH 128
#define DVH 128
#define KEY_DIM 2048
#define VALUE_DIM 4096
#define CONV_DIM 8192
#define BB 2
#define SSEQ 2048
#define MM (BB * SSEQ) /* 4096 rows */
#define CHUNK 64
#define NCHUNK (SSEQ / CHUNK) /* 32 */
#define DVB 16 /* v-cols per recur block */

typedef __hip_bfloat16 bf16;
typedef short short8 __attribute__((ext_vector_type(8)));
typedef float f32x4 __attribute__((ext_vector_type(4)));

__device__ __forceinline__ float bfu(ushort u) {
  union { float f; uint32_t i; } x;
  x.i = ((uint32_t)u) << 16;
  return x.f;
}
__device__ __forceinline__ ushort f2b(float f) {
  bf16 h = __float2bfloat16(f);
  return *reinterpret_cast<ushort*>(&h);
}

__device__ __forceinline__ void gload16(const void* g, const void* l) {
  __builtin_amdgcn_global_load_lds(
      (const __attribute__((address_space(1))) unsigned int*)g,
      (__attribute__((address_space(3))) unsigned int*)(const_cast<void*>(l)),
      16, 0, 0);
}

// swizzled LDS indexers (break D=128/D=64 row-major bank pathology)
__device__ __forceinline__ int kidx(int r, int d) {  // [*][128] bf16
  return r * 128 + (((d >> 3) ^ (r & 7)) << 3) + (d & 7);
}
__device__ __forceinline__ int widx(int r, int d) {  // [*][64] bf16
  return r * 64 + (((d >> 3) ^ (r & 7)) << 3) + (d & 7);
}

// ---------------- cast fp32 -> bf16 ----------------------------------------
__global__ __launch_bounds__(256) void cast_bf16_kernel(
    const float* __restrict__ in, ushort* __restrict__ out, int n4) {
  int i = blockIdx.x * 256 + threadIdx.x;
  if (i < n4) {
    float4 v = ((const float4*)in)[i];
    ushort4 u;
    u.x = f2b(v.x); u.y = f2b(v.y); u.z = f2b(v.z); u.w = f2b(v.w);
    ((ushort4*)out)[i] = u;
  }
}

// ---------------- transpose + cast: W[K,N] fp32 -> WT[N,K] bf16 ------------
__global__ __launch_bounds__(256) void transpose_cast(
    const float* __restrict__ W, ushort* __restrict__ WT, int K, int N) {
  __shared__ ushort tile[32][33];
  const int tx = threadIdx.x & 31, ty = threadIdx.x >> 5;
  const int n0 = blockIdx.x * 32, k0 = blockIdx.y * 32;
#pragma unroll
  for (int i = 0; i < 4; ++i)
    tile[ty + i * 8][tx] = f2b(W[(size_t)(k0 + ty + i * 8) * N + n0 + tx]);
  __syncthreads();
#pragma unroll
  for (int i = 0; i < 4; ++i)
    WT[(size_t)(n0 + ty + i * 8) * K + k0 + tx] = tile[tx][ty + i * 8];
}

// ---------------- bf16 MFMA GEMM: C[M,N] = A[M,K] @ BT[N,K]^T --------------
// 128x128 tile, BK=64; XCD-swizzled block map; LDS-staged bf16 epilogue.
template <bool BF16_OUT>
__global__ __launch_bounds__(256) void gemm_mfma(
    const ushort* __restrict__ A, const ushort* __restrict__ BT,
    void* __restrict__ Cv, int M, int N, int K) {
  __shared__ ushort smem[2 * 128 * 64];  // As | Bs ; epilogue reuses as 128x128
  ushort* As = smem;
  ushort* Bs = smem + 128 * 64;
  const int t = threadIdx.x;
  const int w = t >> 6, lane = t & 63;
  // XCD-aware bijective swizzle (nwg % 8 == 0 for all our shapes)
  const int nwg = gridDim.x * gridDim.y;
  const int lid = blockIdx.y * gridDim.x + blockIdx.x;
  const int swz = (lid & 7) * (nwg >> 3) + (lid >> 3);
  const int m0 = (swz / gridDim.x) * 128, n0 = (swz % gridDim.x) * 128;
  const int srow = lane >> 3;
  const int scol = (lane & 7) * 8;
  const int wm = (w >> 1) * 64, wn = (w & 1) * 64;
  const int fr = lane & 15, kb = lane >> 4;
  f32x4 acc[4][4] = {};

  for (int k0 = 0; k0 < K; k0 += 64) {
#pragma unroll
    for (int i = 0; i < 4; ++i) {
      const int row = (i * 4 + w) * 8 + srow;
      gload16(&A[(size_t)(m0 + row) * K + k0 + scol], &As[row * 64 + scol]);
      gload16(&BT[(size_t)(n0 + row) * K + k0 + scol], &Bs[row * 64 + scol]);
    }
    __syncthreads();
#pragma unroll
    for (int ks = 0; ks < 2; ++ks) {
      const int ka = ks * 32 + kb * 8;
      short8 af[4], bfr[4];
#pragma unroll
      for (int mf = 0; mf < 4; ++mf)
        af[mf] = *(const short8*)&As[(wm + mf * 16 + fr) * 64 + ka];
#pragma unroll
      for (int nf = 0; nf < 4; ++nf)
        bfr[nf] = *(const short8*)&Bs[(wn + nf * 16 + fr) * 64 + ka];
#pragma unroll
      for (int mf = 0; mf < 4; ++mf)
#pragma unroll
        for (int nf = 0; nf < 4; ++nf)
          acc[mf][nf] = __builtin_amdgcn_mfma_f32_16x16x32_bf16(
              af[mf], bfr[nf], acc[mf][nf], 0, 0, 0);
    }
    __syncthreads();
  }
  const int crow = wm + (lane >> 4) * 4;
  const int ccol = wn + fr;
  if constexpr (BF16_OUT) {
    // stage C in LDS (reuses As/Bs: 128x128 ushort), then coalesced dwordx4
#pragma unroll
    for (int mf = 0; mf < 4; ++mf)
#pragma unroll
      for (int nf = 0; nf < 4; ++nf)
#pragma unroll
        for (int j = 0; j < 4; ++j)
          smem[(crow + mf * 16 + j) * 128 + ccol + nf * 16] =
              f2b(acc[mf][nf][j]);
    __syncthreads();
#pragma unroll
    for (int it = 0; it < 8; ++it) {
      const int r = it * 16 + (t >> 4), cch = (t & 15) * 8;
      *(short8*)&((ushort*)Cv)[(size_t)(m0 + r) * N + n0 + cch] =
          *(const short8*)&smem[r * 128 + cch];
    }
  } else {
#pragma unroll
    for (int mf = 0; mf < 4; ++mf)
#pragma unroll
      for (int nf = 0; nf < 4; ++nf)
#pragma unroll
        for (int j = 0; j < 4; ++j)
          ((float*)Cv)[(size_t)(m0 + crow + mf * 16 + j) * N + n0 + ccol +
                       nf * 16] = acc[mf][nf][j];
  }
}

// ---------------- b/a projections + gates (8 rows/block) -------------------
__global__ __launch_bounds__(256) void ba_kernel(
    const float* __restrict__ hs, const float* __restrict__ w_b,
    const float* __restrict__ w_a, const float* __restrict__ dt_bias,
    const float* __restrict__ A_log, float* __restrict__ gbuf,
    float* __restrict__ beta) {
  const int row0 = blockIdx.x * 8;
  const int t = threadIdx.x;
  __shared__ float hsr[8][HSZ];  // 64 KB
  __shared__ float red[2][256];
  {
    const float4* src = (const float4*)(hs + (size_t)row0 * HSZ);
    for (int i = t; i < 8 * HSZ / 4; i += 256) ((float4*)hsr)[i] = src[i];
  }
  __syncthreads();
  const int h = t & 31, p = t >> 5;  // head, partial (8 over k)
  float sb[8] = {}, sa[8] = {};
  const int kbeg = p * 256;
  for (int k = kbeg; k < kbeg + 256; ++k) {
    float wb = w_b[k * NUM_V_HEADS + h];
    float wa = w_a[k * NUM_V_HEADS + h];
#pragma unroll
    for (int r = 0; r < 8; ++r) {
      float x = hsr[r][k];
      sb[r] += x * wb;
      sa[r] += x * wa;
    }
  }
#pragma unroll
  for (int r = 0; r < 8; ++r) {
    red[0][t] = sb[r];
    red[1][t] = sa[r];
    __syncthreads();
    if (t < NUM_V_HEADS) {
      float b = 0.f, a = 0.f;
#pragma unroll
      for (int q = 0; q < 8; ++q) {
        b += red[0][t + 32 * q];
        a += red[1][t + 32 * q];
      }
      float bet = 1.f / (1.f + expf(-b));
      float x = a + dt_bias[t];
      float sp = (x > 20.f) ? x : log1pf(expf(x));
      gbuf[(size_t)(row0 + r) * NUM_V_HEADS + t] = -expf(A_log[t]) * sp;
      beta[(size_t)(row0 + r) * NUM_V_HEADS + t] = bet;
    }
    __syncthreads();
  }
}

// ---------------- causal conv + silu + l2norm (bf16) -----------------------
__global__ __launch_bounds__(256) void conv_kernel(
    const ushort* __restrict__ mixed, const float* __restrict__ conv_w,
    ushort* __restrict__ qkv) {
  const int row = blockIdx.x;
  const int s = row & (SSEQ - 1);
  const int t = threadIdx.x;
  __shared__ float buf[CONV_DIM];
  const ushort* mrow = mixed + (size_t)row * CONV_DIM;
  for (int c = t; c < CONV_DIM; c += 256) {
    float accv = 0.f;
#pragma unroll
    for (int j = 0; j < 4; ++j) {
      int ds = s - 3 + j;
      if (ds >= 0)
        accv += bfu(mrow[(ptrdiff_t)(ds - s) * CONV_DIM + c]) * conv_w[c * 4 + j];
    }
    buf[c] = accv / (1.f + expf(-accv));
  }
  __syncthreads();
  const int grp = t >> 3, r = t & 7;
  const float* gp = buf + grp * DKH + r * 16;
  float ssq = 0.f;
#pragma unroll
  for (int i = 0; i < 16; ++i) {
    float x = gp[i];
    ssq += x * x;
  }
  ssq += __shfl_xor(ssq, 1, 64);
  ssq += __shfl_xor(ssq, 2, 64);
  ssq += __shfl_xor(ssq, 4, 64);
  float sc = rsqrtf(ssq + 1e-6f);
  if (grp < 16) sc *= 0.08838834764831845f;
  ushort* orow = qkv + (size_t)row * CONV_DIM;
#pragma unroll
  for (int i = 0; i < 16; ++i) orow[grp * DKH + r * 16 + i] = f2b(gp[i] * sc);
  for (int c = 2 * KEY_DIM + t; c < CONV_DIM; c += 256) orow[c] = f2b(buf[c]);
}

// ---------------- stage 1: per-chunk T = (I+A)^{-1} and W ------------------
// grid = 2048: c = bid&31, h = (bid>>5)&31, b = bid>>10. 256 thr.
__global__ __launch_bounds__(256) void chunk_T_kernel(
    const ushort* __restrict__ qkv, const float* __restrict__ gbuf,
    const float* __restrict__ beta, ushort* __restrict__ Tbuf,
    ushort* __restrict__ Wbuf) {
  const int bid = blockIdx.x;
  const int c = bid & 31;
  const int h = (bid >> 5) & 31;
  const int b = bid >> 10;
  const int hk = h >> 1;
  const int t = threadIdx.x;
  const int w = t >> 6, lane = t & 63;
  const int fr = lane & 15, fq = lane >> 4;

  __shared__ ushort Klds[64 * 128];           // 16 KB
  __shared__ ushort Qlds[64 * 128];           // 16 KB
  __shared__ __align__(16) float AT[64][68];  // 17.4 KB, AT[j][i] = A[i][j]
  __shared__ ushort Wlds[64 * 64];            // 8 KB (widx layout)
  __shared__ float Gs[64], Bsh[64];

  const int row0 = b * SSEQ + c * CHUNK;
  const int qcol = hk * DKH;
  const int kcol = KEY_DIM + hk * DKH;

#pragma unroll
  for (int r = 0; r < 4; ++r) {
    int vi = t + 256 * r;
    int row = vi >> 4, gr = vi & 15;
    const size_t gb = (size_t)(row0 + row) * CONV_DIM;
    *(short8*)&Klds[row * 128 + ((gr ^ (row & 7)) << 3)] =
        *(const short8*)&qkv[gb + kcol + gr * 8];
    *(short8*)&Qlds[row * 128 + ((gr ^ (row & 7)) << 3)] =
        *(const short8*)&qkv[gb + qcol + gr * 8];
  }
  if (t < 64) {
    float s = gbuf[(size_t)(row0 + t) * NUM_V_HEADS + h];
#pragma unroll
    for (int off = 1; off < 64; off <<= 1) {
      float p = __shfl_up(s, off, 64);
      if (lane >= off) s += p;
    }
    Gs[t] = s;
    Bsh[t] = beta[(size_t)(row0 + t) * NUM_V_HEADS + h];
  }
  __syncthreads();

  // KK^T -> AT ; QK^T -> Wlds
  f32x4 kkt[4] = {}, qkt[4] = {};
#pragma unroll
  for (int ks = 0; ks < 4; ++ks) {
    int d0 = ks * 32 + fq * 8;
    short8 xk = *(const short8*)&Klds[kidx(w * 16 + fr, d0)];
    short8 xq = *(const short8*)&Qlds[kidx(w * 16 + fr, d0)];
#pragma unroll
    for (int j = 0; j < 4; ++j) {
      short8 yk = *(const short8*)&Klds[kidx(j * 16 + fr, d0)];
      kkt[j] = __builtin_amdgcn_mfma_f32_16x16x32_bf16(xk, yk, kkt[j], 0, 0, 0);
      qkt[j] = __builtin_amdgcn_mfma_f32_16x16x32_bf16(xq, yk, qkt[j], 0, 0, 0);
    }
  }
#pragma unroll
  for (int j = 0; j < 4; ++j)
#pragma unroll
    for (int jj = 0; jj < 4; ++jj) {
      int i = w * 16 + fq * 4 + jj;
      int jc = j * 16 + fr;
      AT[jc][i] = (jc < i) ? Bsh[i] * __expf(Gs[i] - Gs[jc]) * kkt[j][jj] : 0.f;
      float val = (jc <= i) ? __expf(Gs[i] - Gs[jc]) * qkt[j][jj] : 0.f;
      Wlds[widx(i, jc)] = f2b(val);
    }
  __syncthreads();

  // dump W (coalesced; layout already widx-swizzled)
  {
    ushort* Wg = Wbuf + (size_t)bid * 4096;
#pragma unroll
    for (int e = 0; e < 8; ++e)
      ((uint*)Wg)[e * 256 + t] = ((const uint*)Wlds)[e * 256 + t];
  }

  // wave 0: in-register forward substitution, lane = column of T
  if (w == 0) {
    float u[64];
#pragma unroll
    for (int i = 0; i < 64; ++i) u[i] = (i == lane) ? 1.f : 0.f;
#pragma unroll
    for (int j = 0; j < 63; ++j) {
      float xj = u[j];
      const int i0 = (j + 1) & ~3;
#pragma unroll
      for (int ii = i0; ii < 64; ii += 4) {
        float4 a4 = *(const float4*)&AT[j][ii];  // broadcast, aligned
        if (ii + 0 > j) u[ii + 0] -= a4.x * xj;
        if (ii + 1 > j) u[ii + 1] -= a4.y * xj;
        if (ii + 2 > j) u[ii + 2] -= a4.z * xj;
        if (ii + 3 > j) u[ii + 3] -= a4.w * xj;
      }
    }
    ushort* Tg = Tbuf + (size_t)bid * 4096;
#pragma unroll
    for (int i = 0; i < 64; ++i) Tg[i * 64 + lane] = f2b(u[i]);  // coalesced
  }
}

// ---------------- stage 2: sequential chunk loop (no solve, no QK^T) -------
// grid = 512: (b:2) x (h:32) x (dvq:8, DVB=16). 256 thr, 2 blocks/CU.
__global__ __launch_bounds__(256, 2) void recur_chunk_kernel(
    const ushort* __restrict__ qkv, const float* __restrict__ gbuf,
    const float* __restrict__ beta, const ushort* __restrict__ Tbuf,
    const ushort* __restrict__ Wbuf, float* __restrict__ o) {
  const int bid = blockIdx.x;
  const int dvq = bid & 7;
  const int h = (bid >> 3) & 31;
  const int b = bid >> 8;
  const int hk = h >> 1;
  const int t = threadIdx.x;
  const int w = t >> 6, lane = t & 63;
  const int fr = lane & 15, fq = lane >> 4;

  __shared__ ushort Klds[64 * 128];  // 16 KB
  __shared__ ushort Vlds[64 * DVB];  // 2 KB
  __shared__ ushort Sth[DVB * 128];  // 4 KB  S0^T hi
  __shared__ ushort Stl[DVB * 128];  // 4 KB  S0^T lo
  __shared__ ushort Th[64 * 64];     // 8 KB  T (widx)
  __shared__ ushort Wlds[64 * 64];   // 8 KB  W (widx, precomputed)
  __shared__ ushort Ut[DVB * 64];    // 2 KB  RHS^T (widx)
  __shared__ ushort UTs[DVB * 64];   // 2 KB  exp(G63-Gi)*u
  __shared__ ushort UTo[DVB * 64];   // 2 KB  plain u
  __shared__ float Gs[64], Bsh[64];

  float sreg[2][4] = {};  // S[(w*2+dt)*16 + fq*4 + jj][fr]

  const int qcol = hk * DKH;
  const int kcol = KEY_DIM + hk * DKH;
  const int vcol = 2 * KEY_DIM + h * DVH + dvq * DVB;
  const int ocol = h * DVH + dvq * DVB;
  const size_t tbase0 = ((size_t)(b * 32 + h) * 32) * 4096;

  for (int c = 0; c < NCHUNK; ++c) {
    const int row0 = b * SSEQ + c * CHUNK;

    // ---- P1: Q->regs, T/W->LDS, K/V->LDS, gates, S->hi/lo ----------------
    short8 xq[4];
#pragma unroll
    for (int ks = 0; ks < 4; ++ks)
      xq[ks] = *(const short8*)&qkv[(size_t)(row0 + w * 16 + fr) * CONV_DIM +
                                    qcol + ks * 32 + fq * 8];
    const ushort* Tg = Tbuf + tbase0 + (size_t)c * 4096;
    const ushort* Wg = Wbuf + tbase0 + (size_t)c * 4096;
    short8 tv0 = *(const short8*)&Tg[t * 16];
    short8 tv1 = *(const short8*)&Tg[t * 16 + 8];
#pragma unroll
    for (int e = 0; e < 8; ++e)
      ((uint*)Wlds)[e * 256 + t] = ((const uint*)Wg)[e * 256 + t];
#pragma unroll
    for (int r = 0; r < 4; ++r) {
      int vi = t + 256 * r;
      int row = vi >> 4, gr = vi & 15;
      *(short8*)&Klds[row * 128 + ((gr ^ (row & 7)) << 3)] =
          *(const short8*)&qkv[(size_t)(row0 + row) * CONV_DIM + kcol + gr * 8];
    }
    if (t < 128) {
      int row = t >> 1, c0 = (t & 1) * 8;
      *(short8*)&Vlds[row * DVB + c0] =
          *(const short8*)&qkv[(size_t)(row0 + row) * CONV_DIM + vcol + c0];
    }
    if (t < 64) {
      float s = gbuf[(size_t)(row0 + t) * NUM_V_HEADS + h];
#pragma unroll
      for (int off = 1; off < 64; off <<= 1) {
        float p = __shfl_up(s, off, 64);
        if (lane >= off) s += p;
      }
      Gs[t] = s;
      Bsh[t] = beta[(size_t)(row0 + t) * NUM_V_HEADS + h];
    }
#pragma unroll
    for (int dt = 0; dt < 2; ++dt)
#pragma unroll
      for (int jj = 0; jj < 4; ++jj) {
        int d = (w * 2 + dt) * 16 + fq * 4 + jj;
        float f = sreg[dt][jj];
        ushort hi = f2b(f);
        int idx = kidx(fr, d);
        Sth[idx] = hi;
        Stl[idx] = f2b(f - bfu(hi));
      }
    {
      int r = t >> 2, d0 = (t & 3) * 16;
      *(short8*)&Th[widx(r, d0)] = tv0;
      *(short8*)&Th[widx(r, d0 + 8)] = tv1;
    }
    __syncthreads();  // B1

    // ---- P2: ks0, qs0; RHS -> Ut; oacc init ------------------------------
    f32x4 ks0 = {}, qs0 = {};
#pragma unroll
    for (int ks = 0; ks < 4; ++ks) {
      int d0 = ks * 32 + fq * 8;
      short8 xk = *(const short8*)&Klds[kidx(w * 16 + fr, d0)];
      short8 yh = *(const short8*)&Sth[kidx(fr, d0)];
      short8 yl = *(const short8*)&Stl[kidx(fr, d0)];
      ks0 = __builtin_amdgcn_mfma_f32_16x16x32_bf16(xk, yh, ks0, 0, 0, 0);
      ks0 = __builtin_amdgcn_mfma_f32_16x16x32_bf16(xk, yl, ks0, 0, 0, 0);
      qs0 = __builtin_amdgcn_mfma_f32_16x16x32_bf16(xq[ks], yh, qs0, 0, 0, 0);
      qs0 = __builtin_amdgcn_mfma_f32_16x16x32_bf16(xq[ks], yl, qs0, 0, 0, 0);
    }
    f32x4 oacc;
#pragma unroll
    for (int jj = 0; jj < 4; ++jj) {
      int i = w * 16 + fq * 4 + jj;
      float eg = __expf(Gs[i]);
      float rhs = Bsh[i] * (bfu(Vlds[i * DVB + fr]) - eg * ks0[jj]);
      Ut[widx(fr, i)] = f2b(rhs);
      oacc[jj] = qs0[jj] * eg;
    }
    __syncthreads();  // B2

    // ---- P3: U = Th @ Ut (MFMA); write UTo / UTs -------------------------
    {
      f32x4 uacc = {};
#pragma unroll
      for (int ks = 0; ks < 2; ++ks) {
        int j0 = ks * 32 + fq * 8;
        short8 ta = *(const short8*)&Th[widx(w * 16 + fr, j0)];
        short8 ub = *(const short8*)&Ut[widx(fr, j0)];
        uacc = __builtin_amdgcn_mfma_f32_16x16x32_bf16(ta, ub, uacc, 0, 0, 0);
      }
#pragma unroll
      for (int jj = 0; jj < 4; ++jj) {
        int i = w * 16 + fq * 4 + jj;
        float u = uacc[jj];
        UTo[widx(fr, i)] = f2b(u);
        UTs[widx(fr, i)] = f2b(u * __expf(Gs[63] - Gs[i]));
      }
    }
    __syncthreads();  // B3

    // ---- P4: O = oacc + W@U; store; S := e^G63 S + K^T @ Us --------------
#pragma unroll
    for (int ks = 0; ks < 2; ++ks) {
      int i0 = ks * 32 + fq * 8;
      short8 xw = *(const short8*)&Wlds[widx(w * 16 + fr, i0)];
      short8 yu = *(const short8*)&UTo[widx(fr, i0)];
      oacc = __builtin_amdgcn_mfma_f32_16x16x32_bf16(xw, yu, oacc, 0, 0, 0);
    }
#pragma unroll
    for (int jj = 0; jj < 4; ++jj) {
      int tt = w * 16 + fq * 4 + jj;
      o[(size_t)(row0 + tt) * VALUE_DIM + ocol + fr] = oacc[jj];
    }
    {
      float eGC = __expf(Gs[63]);
#pragma unroll
      for (int dt = 0; dt < 2; ++dt) {
        const int dk0 = (w * 2 + dt) * 16;
        f32x4 sacc;
#pragma unroll
        for (int jj = 0; jj < 4; ++jj) sacc[jj] = sreg[dt][jj] * eGC;
        const int dkr = dk0 + fr;
#pragma unroll
        for (int ks = 0; ks < 2; ++ks) {
          short8 xk;
#pragma unroll
          for (int e = 0; e < 8; ++e)
            xk[e] = (short)Klds[kidx(ks * 32 + fq * 8 + e, dkr)];
          short8 yu = *(const short8*)&UTs[widx(fr, ks * 32 + fq * 8)];
          sacc = __builtin_amdgcn_mfma_f32_16x16x32_bf16(xk, yu, sacc, 0, 0, 0);
        }
#pragma unroll
        for (int jj = 0; jj < 4; ++jj) sreg[dt][jj] = sacc[jj];
      }
    }
    __syncthreads();  // B4 (protect LDS for next chunk's P1)
  }
}

// ---------------- gated RMSNorm -> bf16 ------------------------------------
__global__ __launch_bounds__(256) void gnorm_kernel(
    const float* __restrict__ o, const ushort* __restrict__ z,
    const float* __restrict__ gamma, ushort* __restrict__ ob) {
  const int row = blockIdx.x;
  const int t = threadIdx.x;
  const int grp = t >> 3, r = t & 7;
  const float* op = o + (size_t)row * VALUE_DIM + grp * DVH + r * 16;
  const ushort* zp = z + (size_t)row * VALUE_DIM + grp * DVH + r * 16;
  ushort* obp = ob + (size_t)row * VALUE_DIM + grp * DVH + r * 16;
  float vals[16];
  float ssq = 0.f;
#pragma unroll
  for (int i = 0; i < 16; ++i) {
    float zz = bfu(zp[i]);
    float x = op[i] * (zz / (1.f + expf(-zz)));
    vals[i] = x;
    ssq += x * x;
  }
  ssq += __shfl_xor(ssq, 1, 64);
  ssq += __shfl_xor(ssq, 2, 64);
  ssq += __shfl_xor(ssq, 4, 64);
  float sc = rsqrtf(ssq * (1.f / 128.f) + 1e-6f);
#pragma unroll
  for (int i = 0; i < 16; ++i) obp[i] = f2b(vals[i] * sc * gamma[r * 16 + i]);
}

// ---------------------------------------------------------------------------
extern "C" void kernel_launch(void* const* d_in, const int* in_sizes, int n_in,
                              void* d_out, int out_size, void* d_ws,
                              size_t ws_size, hipStream_t stream) {
  const float* hs = (const float*)d_in[0];
  const float* w_qkv = (const float*)d_in[1];
  const float* w_z = (const float*)d_in[2];
  const float* w_b = (const float*)d_in[3];
  const float* w_a = (const float*)d_in[4];
  const float* conv_w = (const float*)d_in[5];
  const float* dt_bias = (const float*)d_in[6];
  const float* A_log = (const float*)d_in[7];
  const float* gamma = (const float*)d_in[8];
  const float* w_out = (const float*)d_in[9];
  float* out = (float*)d_out;
  char* wsb = (char*)d_ws;

  // workspace layout (241 MiB total)
  ushort* hs_b = (ushort*)wsb;                      // 16 MiB (later: Tbuf)
  ushort* wqkvT = hs_b + (size_t)MM * HSZ;          // 32 MiB (later: Wbuf)
  ushort* wzT = wqkvT + (size_t)CONV_DIM * HSZ;     // 16 MiB
  ushort* woutT = wzT + (size_t)VALUE_DIM * HSZ;    // 16 MiB
  ushort* mixed = woutT + (size_t)HSZ * VALUE_DIM;  // 64 MiB bf16
  ushort* qkv = mixed + (size_t)MM * CONV_DIM;      // 64 MiB bf16
  ushort* z = qkv + (size_t)MM * CONV_DIM;          // 32 MiB bf16
  float* gbuf = (float*)(z + (size_t)MM * VALUE_DIM);
  float* beta = gbuf + (size_t)MM * NUM_V_HEADS;
  float* o = (float*)mixed;   // fp32, aliases retired mixed (64 MiB)
  ushort* ob = qkv;           // bf16, aliases retired qkv
  ushort* Tbuf = hs_b;        // 16 MiB, aliases retired hs_b
  ushort* Wbuf = wqkvT;       // 16 MiB, aliases retired wqkvT

  cast_bf16_kernel<<<(MM * HSZ / 4 + 255) / 256, 256, 0, stream>>>(
      hs, hs_b, MM * HSZ / 4);
  transpose_cast<<<dim3(CONV_DIM / 32, HSZ / 32), 256, 0, stream>>>(
      w_qkv, wqkvT, HSZ, CONV_DIM);
  transpose_cast<<<dim3(VALUE_DIM / 32, HSZ / 32), 256, 0, stream>>>(
      w_z, wzT, HSZ, VALUE_DIM);
  transpose_cast<<<dim3(HSZ / 32, VALUE_DIM / 32), 256, 0, stream>>>(
      w_out, woutT, VALUE_DIM, HSZ);

  gemm_mfma<true><<<dim3(CONV_DIM / 128, MM / 128), 256, 0, stream>>>(
      hs_b, wqkvT, mixed, MM, CONV_DIM, HSZ);
  gemm_mfma<true><<<dim3(VALUE_DIM / 128, MM / 128), 256, 0, stream>>>(
      hs_b, wzT, z, MM, VALUE_DIM, HSZ);
  ba_kernel<<<MM / 8, 256, 0, stream>>>(hs, w_b, w_a, dt_bias, A_log, gbuf,
                                        beta);
  conv_kernel<<<MM, 256, 0, stream>>>(mixed, conv_w, qkv);
  chunk_T_kernel<<<2048, 256, 0, stream>>>(qkv, gbuf, beta, Tbuf, Wbuf);
  recur_chunk_kernel<<<512, 256, 0, stream>>>(qkv, gbuf, beta, Tbuf, Wbuf, o);
  gnorm_kernel<<<MM, 256, 0, stream>>>(o, z, gamma, ob);
  gemm_mfma<false><<<dim3(HSZ / 128, MM / 128), 256, 0, stream>>>(
      ob, woutT, out, MM, HSZ, VALUE_DIM);
}

// Round 10
// 977.845 us; speedup vs baseline: 1.3386x; 1.0043x over previous
//
#include <hip/hip_runtime.h>
#include <hip/hip_bf16.h>
#include <cstdint>

// ---------------------------------------------------------------------------
// Qwen3.5 GatedDeltaNet — round 10: GEMM rebuilt as 256^2-tile, 8-wave,
// counted-vmcnt double-buffered pipeline (no vmcnt(0) drain in the K-loop).
// XCD swizzle dropped (round-9 evidence: neutral time, 4x L2-fill).
// All other kernels unchanged from round 9 (passed, absmax 0.0234).
// ---------------------------------------------------------------------------

#define HSZ 2048
#define NUM_K_HEADS 16
#define NUM_V_HEADS 32
#define DKH 128
#define DVH 128
#define KEY_DIM 2048
#define VALUE_DIM 4096
#define CONV_DIM 8192
#define BB 2
#define SSEQ 2048
#define MM (BB * SSEQ) /* 4096 rows */
#define CHUNK 64
#define NCHUNK (SSEQ / CHUNK) /* 32 */
#define DVB 16 /* v-cols per recur block */

typedef __hip_bfloat16 bf16;
typedef short short8 __attribute__((ext_vector_type(8)));
typedef float f32x4 __attribute__((ext_vector_type(4)));

__device__ __forceinline__ float bfu(ushort u) {
  union { float f; uint32_t i; } x;
  x.i = ((uint32_t)u) << 16;
  return x.f;
}
__device__ __forceinline__ ushort f2b(float f) {
  bf16 h = __float2bfloat16(f);
  return *reinterpret_cast<ushort*>(&h);
}

__device__ __forceinline__ void gload16(const void* g, const void* l) {
  __builtin_amdgcn_global_load_lds(
      (const __attribute__((address_space(1))) unsigned int*)g,
      (__attribute__((address_space(3))) unsigned int*)(const_cast<void*>(l)),
      16, 0, 0);
}

// swizzled LDS indexers (break D=128/D=64 row-major bank pathology)
__device__ __forceinline__ int kidx(int r, int d) {  // [*][128] bf16
  return r * 128 + (((d >> 3) ^ (r & 7)) << 3) + (d & 7);
}
__device__ __forceinline__ int widx(int r, int d) {  // [*][64] bf16
  return r * 64 + (((d >> 3) ^ (r & 7)) << 3) + (d & 7);
}

// ---------------- cast fp32 -> bf16 ----------------------------------------
__global__ __launch_bounds__(256) void cast_bf16_kernel(
    const float* __restrict__ in, ushort* __restrict__ out, int n4) {
  int i = blockIdx.x * 256 + threadIdx.x;
  if (i < n4) {
    float4 v = ((const float4*)in)[i];
    ushort4 u;
    u.x = f2b(v.x); u.y = f2b(v.y); u.z = f2b(v.z); u.w = f2b(v.w);
    ((ushort4*)out)[i] = u;
  }
}

// ---------------- transpose + cast: W[K,N] fp32 -> WT[N,K] bf16 ------------
__global__ __launch_bounds__(256) void transpose_cast(
    const float* __restrict__ W, ushort* __restrict__ WT, int K, int N) {
  __shared__ ushort tile[32][33];
  const int tx = threadIdx.x & 31, ty = threadIdx.x >> 5;
  const int n0 = blockIdx.x * 32, k0 = blockIdx.y * 32;
#pragma unroll
  for (int i = 0; i < 4; ++i)
    tile[ty + i * 8][tx] = f2b(W[(size_t)(k0 + ty + i * 8) * N + n0 + tx]);
  __syncthreads();
#pragma unroll
  for (int i = 0; i < 4; ++i)
    WT[(size_t)(n0 + ty + i * 8) * K + k0 + tx] = tile[tx][ty + i * 8];
}

// ---------------- bf16 MFMA GEMM: C[M,N] = A[M,K] @ BT[N,K]^T --------------
// 256x256 tile, BK=64, 512 thr (8 waves, 2Mx4N), per-wave 128x64 output.
// Counted-vmcnt double-buffered global_load_lds pipeline; raw s_barrier.
template <bool BF16_OUT>
__global__ __launch_bounds__(512) void gemm256(
    const ushort* __restrict__ A, const ushort* __restrict__ BT,
    void* __restrict__ Cv, int M, int N, int K) {
  // staging: 2 bufs x (A 16384 + B 16384) ushort = 65536; epilogue 256x264
  __shared__ __align__(16) ushort smem[256 * 264];  // 132 KiB
  const int t = threadIdx.x;
  const int w = t >> 6, lane = t & 63;
  const int m0 = blockIdx.y * 256, n0 = blockIdx.x * 256;
  const int wm = (w >> 2) * 128, wn = (w & 3) * 64;
  const int fr = lane & 15, kb = lane >> 4;
  const int srow = t >> 3;       // 0..63
  const int scol = (t & 7) * 8;  // bf16 col (16B granule)
  f32x4 acc[8][4] = {};
  const int nt = K / 64;

#define STAGE_TILE(tt, buf)                                                   \
  {                                                                           \
    const int k0_ = (tt)*64;                                                  \
    ushort* As_ = smem + (buf)*32768;                                         \
    ushort* Bs_ = As_ + 16384;                                                \
    _Pragma("unroll") for (int p = 0; p < 4; ++p) {                           \
      const int row_ = p * 64 + srow;                                         \
      gload16(&A[(size_t)(m0 + row_) * K + k0_ + scol],                       \
              &As_[row_ * 64 + scol]);                                        \
    }                                                                         \
    _Pragma("unroll") for (int p = 0; p < 4; ++p) {                           \
      const int row_ = p * 64 + srow;                                         \
      gload16(&BT[(size_t)(n0 + row_) * K + k0_ + scol],                      \
              &Bs_[row_ * 64 + scol]);                                        \
    }                                                                         \
  }

  STAGE_TILE(0, 0);
  STAGE_TILE(1, 1);

  for (int tt = 0; tt < nt; ++tt) {
    const int buf = tt & 1;
    const ushort* As = smem + buf * 32768;
    const ushort* Bs = As + 16384;
    // wait for THIS tile's 8 loads (per-wave); next tile's 8 stay in flight
    if (tt + 1 < nt)
      asm volatile("s_waitcnt vmcnt(8)" ::: "memory");
    else
      asm volatile("s_waitcnt vmcnt(0)" ::: "memory");
    __builtin_amdgcn_sched_barrier(0);
    __builtin_amdgcn_s_barrier();  // all waves' tile-tt loads landed
    __builtin_amdgcn_sched_barrier(0);
#pragma unroll
    for (int ks = 0; ks < 2; ++ks) {
      const int ka = ks * 32 + kb * 8;
      short8 af[8], bf_[4];
#pragma unroll
      for (int mf = 0; mf < 8; ++mf)
        af[mf] = *(const short8*)&As[(wm + mf * 16 + fr) * 64 + ka];
#pragma unroll
      for (int nf = 0; nf < 4; ++nf)
        bf_[nf] = *(const short8*)&Bs[(wn + nf * 16 + fr) * 64 + ka];
#pragma unroll
      for (int mf = 0; mf < 8; ++mf)
#pragma unroll
        for (int nf = 0; nf < 4; ++nf)
          acc[mf][nf] = __builtin_amdgcn_mfma_f32_16x16x32_bf16(
              af[mf], bf_[nf], acc[mf][nf], 0, 0, 0);
    }
    __builtin_amdgcn_sched_barrier(0);
    __builtin_amdgcn_s_barrier();  // all waves done reading buf
    __builtin_amdgcn_sched_barrier(0);
    if (tt + 2 < nt) STAGE_TILE(tt + 2, buf);
  }
#undef STAGE_TILE

  const int crow = wm + (lane >> 4) * 4;
  const int ccol = wn + fr;
  if constexpr (BF16_OUT) {
    // stage C in LDS [256][264] (rows 528B, 16B-aligned), then coalesced out
#pragma unroll
    for (int mf = 0; mf < 8; ++mf)
#pragma unroll
      for (int nf = 0; nf < 4; ++nf)
#pragma unroll
        for (int j = 0; j < 4; ++j)
          smem[(crow + mf * 16 + j) * 264 + ccol + nf * 16] =
              f2b(acc[mf][nf][j]);
    __syncthreads();
#pragma unroll
    for (int p = 0; p < 16; ++p) {
      const int r = p * 16 + (t >> 5), cch = (t & 31) * 8;
      *(short8*)&((ushort*)Cv)[(size_t)(m0 + r) * N + n0 + cch] =
          *(const short8*)&smem[r * 264 + cch];
    }
  } else {
#pragma unroll
    for (int mf = 0; mf < 8; ++mf)
#pragma unroll
      for (int nf = 0; nf < 4; ++nf)
#pragma unroll
        for (int j = 0; j < 4; ++j)
          ((float*)Cv)[(size_t)(m0 + crow + mf * 16 + j) * N + n0 + ccol +
                       nf * 16] = acc[mf][nf][j];
  }
}

// ---------------- b/a projections + gates (8 rows/block) -------------------
__global__ __launch_bounds__(256) void ba_kernel(
    const float* __restrict__ hs, const float* __restrict__ w_b,
    const float* __restrict__ w_a, const float* __restrict__ dt_bias,
    const float* __restrict__ A_log, float* __restrict__ gbuf,
    float* __restrict__ beta) {
  const int row0 = blockIdx.x * 8;
  const int t = threadIdx.x;
  __shared__ float hsr[8][HSZ];  // 64 KB
  __shared__ float red[2][256];
  {
    const float4* src = (const float4*)(hs + (size_t)row0 * HSZ);
    for (int i = t; i < 8 * HSZ / 4; i += 256) ((float4*)hsr)[i] = src[i];
  }
  __syncthreads();
  const int h = t & 31, p = t >> 5;  // head, partial (8 over k)
  float sb[8] = {}, sa[8] = {};
  const int kbeg = p * 256;
  for (int k = kbeg; k < kbeg + 256; ++k) {
    float wb = w_b[k * NUM_V_HEADS + h];
    float wa = w_a[k * NUM_V_HEADS + h];
#pragma unroll
    for (int r = 0; r < 8; ++r) {
      float x = hsr[r][k];
      sb[r] += x * wb;
      sa[r] += x * wa;
    }
  }
#pragma unroll
  for (int r = 0; r < 8; ++r) {
    red[0][t] = sb[r];
    red[1][t] = sa[r];
    __syncthreads();
    if (t < NUM_V_HEADS) {
      float b = 0.f, a = 0.f;
#pragma unroll
      for (int q = 0; q < 8; ++q) {
        b += red[0][t + 32 * q];
        a += red[1][t + 32 * q];
      }
      float bet = 1.f / (1.f + expf(-b));
      float x = a + dt_bias[t];
      float sp = (x > 20.f) ? x : log1pf(expf(x));
      gbuf[(size_t)(row0 + r) * NUM_V_HEADS + t] = -expf(A_log[t]) * sp;
      beta[(size_t)(row0 + r) * NUM_V_HEADS + t] = bet;
    }
    __syncthreads();
  }
}

// ---------------- causal conv + silu + l2norm (bf16) -----------------------
__global__ __launch_bounds__(256) void conv_kernel(
    const ushort* __restrict__ mixed, const float* __restrict__ conv_w,
    ushort* __restrict__ qkv) {
  const int row = blockIdx.x;
  const int s = row & (SSEQ - 1);
  const int t = threadIdx.x;
  __shared__ float buf[CONV_DIM];
  const ushort* mrow = mixed + (size_t)row * CONV_DIM;
  for (int c = t; c < CONV_DIM; c += 256) {
    float accv = 0.f;
#pragma unroll
    for (int j = 0; j < 4; ++j) {
      int ds = s - 3 + j;
      if (ds >= 0)
        accv += bfu(mrow[(ptrdiff_t)(ds - s) * CONV_DIM + c]) * conv_w[c * 4 + j];
    }
    buf[c] = accv / (1.f + expf(-accv));
  }
  __syncthreads();
  const int grp = t >> 3, r = t & 7;
  const float* gp = buf + grp * DKH + r * 16;
  float ssq = 0.f;
#pragma unroll
  for (int i = 0; i < 16; ++i) {
    float x = gp[i];
    ssq += x * x;
  }
  ssq += __shfl_xor(ssq, 1, 64);
  ssq += __shfl_xor(ssq, 2, 64);
  ssq += __shfl_xor(ssq, 4, 64);
  float sc = rsqrtf(ssq + 1e-6f);
  if (grp < 16) sc *= 0.08838834764831845f;
  ushort* orow = qkv + (size_t)row * CONV_DIM;
#pragma unroll
  for (int i = 0; i < 16; ++i) orow[grp * DKH + r * 16 + i] = f2b(gp[i] * sc);
  for (int c = 2 * KEY_DIM + t; c < CONV_DIM; c += 256) orow[c] = f2b(buf[c]);
}

// ---------------- stage 1: per-chunk T = (I+A)^{-1} and W ------------------
// grid = 2048: c = bid&31, h = (bid>>5)&31, b = bid>>10. 256 thr.
__global__ __launch_bounds__(256) void chunk_T_kernel(
    const ushort* __restrict__ qkv, const float* __restrict__ gbuf,
    const float* __restrict__ beta, ushort* __restrict__ Tbuf,
    ushort* __restrict__ Wbuf) {
  const int bid = blockIdx.x;
  const int c = bid & 31;
  const int h = (bid >> 5) & 31;
  const int b = bid >> 10;
  const int hk = h >> 1;
  const int t = threadIdx.x;
  const int w = t >> 6, lane = t & 63;
  const int fr = lane & 15, fq = lane >> 4;

  __shared__ ushort Klds[64 * 128];           // 16 KB
  __shared__ ushort Qlds[64 * 128];           // 16 KB
  __shared__ __align__(16) float AT[64][68];  // 17.4 KB, AT[j][i] = A[i][j]
  __shared__ ushort Wlds[64 * 64];            // 8 KB (widx layout)
  __shared__ float Gs[64], Bsh[64];

  const int row0 = b * SSEQ + c * CHUNK;
  const int qcol = hk * DKH;
  const int kcol = KEY_DIM + hk * DKH;

#pragma unroll
  for (int r = 0; r < 4; ++r) {
    int vi = t + 256 * r;
    int row = vi >> 4, gr = vi & 15;
    const size_t gb = (size_t)(row0 + row) * CONV_DIM;
    *(short8*)&Klds[row * 128 + ((gr ^ (row & 7)) << 3)] =
        *(const short8*)&qkv[gb + kcol + gr * 8];
    *(short8*)&Qlds[row * 128 + ((gr ^ (row & 7)) << 3)] =
        *(const short8*)&qkv[gb + qcol + gr * 8];
  }
  if (t < 64) {
    float s = gbuf[(size_t)(row0 + t) * NUM_V_HEADS + h];
#pragma unroll
    for (int off = 1; off < 64; off <<= 1) {
      float p = __shfl_up(s, off, 64);
      if (lane >= off) s += p;
    }
    Gs[t] = s;
    Bsh[t] = beta[(size_t)(row0 + t) * NUM_V_HEADS + h];
  }
  __syncthreads();

  // KK^T -> AT ; QK^T -> Wlds
  f32x4 kkt[4] = {}, qkt[4] = {};
#pragma unroll
  for (int ks = 0; ks < 4; ++ks) {
    int d0 = ks * 32 + fq * 8;
    short8 xk = *(const short8*)&Klds[kidx(w * 16 + fr, d0)];
    short8 xq = *(const short8*)&Qlds[kidx(w * 16 + fr, d0)];
#pragma unroll
    for (int j = 0; j < 4; ++j) {
      short8 yk = *(const short8*)&Klds[kidx(j * 16 + fr, d0)];
      kkt[j] = __builtin_amdgcn_mfma_f32_16x16x32_bf16(xk, yk, kkt[j], 0, 0, 0);
      qkt[j] = __builtin_amdgcn_mfma_f32_16x16x32_bf16(xq, yk, qkt[j], 0, 0, 0);
    }
  }
#pragma unroll
  for (int j = 0; j < 4; ++j)
#pragma unroll
    for (int jj = 0; jj < 4; ++jj) {
      int i = w * 16 + fq * 4 + jj;
      int jc = j * 16 + fr;
      AT[jc][i] = (jc < i) ? Bsh[i] * __expf(Gs[i] - Gs[jc]) * kkt[j][jj] : 0.f;
      float val = (jc <= i) ? __expf(Gs[i] - Gs[jc]) * qkt[j][jj] : 0.f;
      Wlds[widx(i, jc)] = f2b(val);
    }
  __syncthreads();

  // dump W (coalesced; layout already widx-swizzled)
  {
    ushort* Wg = Wbuf + (size_t)bid * 4096;
#pragma unroll
    for (int e = 0; e < 8; ++e)
      ((uint*)Wg)[e * 256 + t] = ((const uint*)Wlds)[e * 256 + t];
  }

  // wave 0: in-register forward substitution, lane = column of T
  if (w == 0) {
    float u[64];
#pragma unroll
    for (int i = 0; i < 64; ++i) u[i] = (i == lane) ? 1.f : 0.f;
#pragma unroll
    for (int j = 0; j < 63; ++j) {
      float xj = u[j];
      const int i0 = (j + 1) & ~3;
#pragma unroll
      for (int ii = i0; ii < 64; ii += 4) {
        float4 a4 = *(const float4*)&AT[j][ii];  // broadcast, aligned
        if (ii + 0 > j) u[ii + 0] -= a4.x * xj;
        if (ii + 1 > j) u[ii + 1] -= a4.y * xj;
        if (ii + 2 > j) u[ii + 2] -= a4.z * xj;
        if (ii + 3 > j) u[ii + 3] -= a4.w * xj;
      }
    }
    ushort* Tg = Tbuf + (size_t)bid * 4096;
#pragma unroll
    for (int i = 0; i < 64; ++i) Tg[i * 64 + lane] = f2b(u[i]);  // coalesced
  }
}

// ---------------- stage 2: sequential chunk loop (no solve, no QK^T) -------
// grid = 512: (b:2) x (h:32) x (dvq:8, DVB=16). 256 thr, 2 blocks/CU.
__global__ __launch_bounds__(256, 2) void recur_chunk_kernel(
    const ushort* __restrict__ qkv, const float* __restrict__ gbuf,
    const float* __restrict__ beta, const ushort* __restrict__ Tbuf,
    const ushort* __restrict__ Wbuf, float* __restrict__ o) {
  const int bid = blockIdx.x;
  const int dvq = bid & 7;
  const int h = (bid >> 3) & 31;
  const int b = bid >> 8;
  const int hk = h >> 1;
  const int t = threadIdx.x;
  const int w = t >> 6, lane = t & 63;
  const int fr = lane & 15, fq = lane >> 4;

  __shared__ ushort Klds[64 * 128];  // 16 KB
  __shared__ ushort Vlds[64 * DVB];  // 2 KB
  __shared__ ushort Sth[DVB * 128];  // 4 KB  S0^T hi
  __shared__ ushort Stl[DVB * 128];  // 4 KB  S0^T lo
  __shared__ ushort Th[64 * 64];     // 8 KB  T (widx)
  __shared__ ushort Wlds[64 * 64];   // 8 KB  W (widx, precomputed)
  __shared__ ushort Ut[DVB * 64];    // 2 KB  RHS^T (widx)
  __shared__ ushort UTs[DVB * 64];   // 2 KB  exp(G63-Gi)*u
  __shared__ ushort UTo[DVB * 64];   // 2 KB  plain u
  __shared__ float Gs[64], Bsh[64];

  float sreg[2][4] = {};  // S[(w*2+dt)*16 + fq*4 + jj][fr]

  const int qcol = hk * DKH;
  const int kcol = KEY_DIM + hk * DKH;
  const int vcol = 2 * KEY_DIM + h * DVH + dvq * DVB;
  const int ocol = h * DVH + dvq * DVB;
  const size_t tbase0 = ((size_t)(b * 32 + h) * 32) * 4096;

  for (int c = 0; c < NCHUNK; ++c) {
    const int row0 = b * SSEQ + c * CHUNK;

    // ---- P1: Q->regs, T/W->LDS, K/V->LDS, gates, S->hi/lo ----------------
    short8 xq[4];
#pragma unroll
    for (int ks = 0; ks < 4; ++ks)
      xq[ks] = *(const short8*)&qkv[(size_t)(row0 + w * 16 + fr) * CONV_DIM +
                                    qcol + ks * 32 + fq * 8];
    const ushort* Tg = Tbuf + tbase0 + (size_t)c * 4096;
    const ushort* Wg = Wbuf + tbase0 + (size_t)c * 4096;
    short8 tv0 = *(const short8*)&Tg[t * 16];
    short8 tv1 = *(const short8*)&Tg[t * 16 + 8];
#pragma unroll
    for (int e = 0; e < 8; ++e)
      ((uint*)Wlds)[e * 256 + t] = ((const uint*)Wg)[e * 256 + t];
#pragma unroll
    for (int r = 0; r < 4; ++r) {
      int vi = t + 256 * r;
      int row = vi >> 4, gr = vi & 15;
      *(short8*)&Klds[row * 128 + ((gr ^ (row & 7)) << 3)] =
          *(const short8*)&qkv[(size_t)(row0 + row) * CONV_DIM + kcol + gr * 8];
    }
    if (t < 128) {
      int row = t >> 1, c0 = (t & 1) * 8;
      *(short8*)&Vlds[row * DVB + c0] =
          *(const short8*)&qkv[(size_t)(row0 + row) * CONV_DIM + vcol + c0];
    }
    if (t < 64) {
      float s = gbuf[(size_t)(row0 + t) * NUM_V_HEADS + h];
#pragma unroll
      for (int off = 1; off < 64; off <<= 1) {
        float p = __shfl_up(s, off, 64);
        if (lane >= off) s += p;
      }
      Gs[t] = s;
      Bsh[t] = beta[(size_t)(row0 + t) * NUM_V_HEADS + h];
    }
#pragma unroll
    for (int dt = 0; dt < 2; ++dt)
#pragma unroll
      for (int jj = 0; jj < 4; ++jj) {
        int d = (w * 2 + dt) * 16 + fq * 4 + jj;
        float f = sreg[dt][jj];
        ushort hi = f2b(f);
        int idx = kidx(fr, d);
        Sth[idx] = hi;
        Stl[idx] = f2b(f - bfu(hi));
      }
    {
      int r = t >> 2, d0 = (t & 3) * 16;
      *(short8*)&Th[widx(r, d0)] = tv0;
      *(short8*)&Th[widx(r, d0 + 8)] = tv1;
    }
    __syncthreads();  // B1

    // ---- P2: ks0, qs0; RHS -> Ut; oacc init ------------------------------
    f32x4 ks0 = {}, qs0 = {};
#pragma unroll
    for (int ks = 0; ks < 4; ++ks) {
      int d0 = ks * 32 + fq * 8;
      short8 xk = *(const short8*)&Klds[kidx(w * 16 + fr, d0)];
      short8 yh = *(const short8*)&Sth[kidx(fr, d0)];
      short8 yl = *(const short8*)&Stl[kidx(fr, d0)];
      ks0 = __builtin_amdgcn_mfma_f32_16x16x32_bf16(xk, yh, ks0, 0, 0, 0);
      ks0 = __builtin_amdgcn_mfma_f32_16x16x32_bf16(xk, yl, ks0, 0, 0, 0);
      qs0 = __builtin_amdgcn_mfma_f32_16x16x32_bf16(xq[ks], yh, qs0, 0, 0, 0);
      qs0 = __builtin_amdgcn_mfma_f32_16x16x32_bf16(xq[ks], yl, qs0, 0, 0, 0);
    }
    f32x4 oacc;
#pragma unroll
    for (int jj = 0; jj < 4; ++jj) {
      int i = w * 16 + fq * 4 + jj;
      float eg = __expf(Gs[i]);
      float rhs = Bsh[i] * (bfu(Vlds[i * DVB + fr]) - eg * ks0[jj]);
      Ut[widx(fr, i)] = f2b(rhs);
      oacc[jj] = qs0[jj] * eg;
    }
    __syncthreads();  // B2

    // ---- P3: U = Th @ Ut (MFMA); write UTo / UTs -------------------------
    {
      f32x4 uacc = {};
#pragma unroll
      for (int ks = 0; ks < 2; ++ks) {
        int j0 = ks * 32 + fq * 8;
        short8 ta = *(const short8*)&Th[widx(w * 16 + fr, j0)];
        short8 ub = *(const short8*)&Ut[widx(fr, j0)];
        uacc = __builtin_amdgcn_mfma_f32_16x16x32_bf16(ta, ub, uacc, 0, 0, 0);
      }
#pragma unroll
      for (int jj = 0; jj < 4; ++jj) {
        int i = w * 16 + fq * 4 + jj;
        float u = uacc[jj];
        UTo[widx(fr, i)] = f2b(u);
        UTs[widx(fr, i)] = f2b(u * __expf(Gs[63] - Gs[i]));
      }
    }
    __syncthreads();  // B3

    // ---- P4: O = oacc + W@U; store; S := e^G63 S + K^T @ Us --------------
#pragma unroll
    for (int ks = 0; ks < 2; ++ks) {
      int i0 = ks * 32 + fq * 8;
      short8 xw = *(const short8*)&Wlds[widx(w * 16 + fr, i0)];
      short8 yu = *(const short8*)&UTo[widx(fr, i0)];
      oacc = __builtin_amdgcn_mfma_f32_16x16x32_bf16(xw, yu, oacc, 0, 0, 0);
    }
#pragma unroll
    for (int jj = 0; jj < 4; ++jj) {
      int tt = w * 16 + fq * 4 + jj;
      o[(size_t)(row0 + tt) * VALUE_DIM + ocol + fr] = oacc[jj];
    }
    {
      float eGC = __expf(Gs[63]);
#pragma unroll
      for (int dt = 0; dt < 2; ++dt) {
        const int dk0 = (w * 2 + dt) * 16;
        f32x4 sacc;
#pragma unroll
        for (int jj = 0; jj < 4; ++jj) sacc[jj] = sreg[dt][jj] * eGC;
        const int dkr = dk0 + fr;
#pragma unroll
        for (int ks = 0; ks < 2; ++ks) {
          short8 xk;
#pragma unroll
          for (int e = 0; e < 8; ++e)
            xk[e] = (short)Klds[kidx(ks * 32 + fq * 8 + e, dkr)];
          short8 yu = *(const short8*)&UTs[widx(fr, ks * 32 + fq * 8)];
          sacc = __builtin_amdgcn_mfma_f32_16x16x32_bf16(xk, yu, sacc, 0, 0, 0);
        }
#pragma unroll
        for (int jj = 0; jj < 4; ++jj) sreg[dt][jj] = sacc[jj];
      }
    }
    __syncthreads();  // B4 (protect LDS for next chunk's P1)
  }
}

// ---------------- gated RMSNorm -> bf16 ------------------------------------
__global__ __launch_bounds__(256) void gnorm_kernel(
    const float* __restrict__ o, const ushort* __restrict__ z,
    const float* __restrict__ gamma, ushort* __restrict__ ob) {
  const int row = blockIdx.x;
  const int t = threadIdx.x;
  const int grp = t >> 3, r = t & 7;
  const float* op = o + (size_t)row * VALUE_DIM + grp * DVH + r * 16;
  const ushort* zp = z + (size_t)row * VALUE_DIM + grp * DVH + r * 16;
  ushort* obp = ob + (size_t)row * VALUE_DIM + grp * DVH + r * 16;
  float vals[16];
  float ssq = 0.f;
#pragma unroll
  for (int i = 0; i < 16; ++i) {
    float zz = bfu(zp[i]);
    float x = op[i] * (zz / (1.f + expf(-zz)));
    vals[i] = x;
    ssq += x * x;
  }
  ssq += __shfl_xor(ssq, 1, 64);
  ssq += __shfl_xor(ssq, 2, 64);
  ssq += __shfl_xor(ssq, 4, 64);
  float sc = rsqrtf(ssq * (1.f / 128.f) + 1e-6f);
#pragma unroll
  for (int i = 0; i < 16; ++i) obp[i] = f2b(vals[i] * sc * gamma[r * 16 + i]);
}

// ---------------------------------------------------------------------------
extern "C" void kernel_launch(void* const* d_in, const int* in_sizes, int n_in,
                              void* d_out, int out_size, void* d_ws,
                              size_t ws_size, hipStream_t stream) {
  const float* hs = (const float*)d_in[0];
  const float* w_qkv = (const float*)d_in[1];
  const float* w_z = (const float*)d_in[2];
  const float* w_b = (const float*)d_in[3];
  const float* w_a = (const float*)d_in[4];
  const float* conv_w = (const float*)d_in[5];
  const float* dt_bias = (const float*)d_in[6];
  const float* A_log = (const float*)d_in[7];
  const float* gamma = (const float*)d_in[8];
  const float* w_out = (const float*)d_in[9];
  float* out = (float*)d_out;
  char* wsb = (char*)d_ws;

  // workspace layout (241 MiB total)
  ushort* hs_b = (ushort*)wsb;                      // 16 MiB (later: Tbuf)
  ushort* wqkvT = hs_b + (size_t)MM * HSZ;          // 32 MiB (later: Wbuf)
  ushort* wzT = wqkvT + (size_t)CONV_DIM * HSZ;     // 16 MiB
  ushort* woutT = wzT + (size_t)VALUE_DIM * HSZ;    // 16 MiB
  ushort* mixed = woutT + (size_t)HSZ * VALUE_DIM;  // 64 MiB bf16
  ushort* qkv = mixed + (size_t)MM * CONV_DIM;      // 64 MiB bf16
  ushort* z = qkv + (size_t)MM * CONV_DIM;          // 32 MiB bf16
  float* gbuf = (float*)(z + (size_t)MM * VALUE_DIM);
  float* beta = gbuf + (size_t)MM * NUM_V_HEADS;
  float* o = (float*)mixed;   // fp32, aliases retired mixed (64 MiB)
  ushort* ob = qkv;           // bf16, aliases retired qkv
  ushort* Tbuf = hs_b;        // 16 MiB, aliases retired hs_b
  ushort* Wbuf = wqkvT;       // 16 MiB, aliases retired wqkvT

  cast_bf16_kernel<<<(MM * HSZ / 4 + 255) / 256, 256, 0, stream>>>(
      hs, hs_b, MM * HSZ / 4);
  transpose_cast<<<dim3(CONV_DIM / 32, HSZ / 32), 256, 0, stream>>>(
      w_qkv, wqkvT, HSZ, CONV_DIM);
  transpose_cast<<<dim3(VALUE_DIM / 32, HSZ / 32), 256, 0, stream>>>(
      w_z, wzT, HSZ, VALUE_DIM);
  transpose_cast<<<dim3(HSZ / 32, VALUE_DIM / 32), 256, 0, stream>>>(
      w_out, woutT, VALUE_DIM, HSZ);

  gemm256<true><<<dim3(CONV_DIM / 256, MM / 256), 512, 0, stream>>>(
      hs_b, wqkvT, mixed, MM, CONV_DIM, HSZ);
  gemm256<true><<<dim3(VALUE_DIM / 256, MM / 256), 512, 0, stream>>>(
      hs_b, wzT, z, MM, VALUE_DIM, HSZ);
  ba_kernel<<<MM / 8, 256, 0, stream>>>(hs, w_b, w_a, dt_bias, A_log, gbuf,
                                        beta);
  conv_kernel<<<MM, 256, 0, stream>>>(mixed, conv_w, qkv);
  chunk_T_kernel<<<2048, 256, 0, stream>>>(qkv, gbuf, beta, Tbuf, Wbuf);
  recur_chunk_kernel<<<512, 256, 0, stream>>>(qkv, gbuf, beta, Tbuf, Wbuf, o);
  gnorm_kernel<<<MM, 256, 0, stream>>>(o, z, gamma, ob);
  gemm256<false><<<dim3(HSZ / 256, MM / 256), 512, 0, stream>>>(
      ob, woutT, out, MM, HSZ, VALUE_DIM);
}

// Round 11
// 867.943 us; speedup vs baseline: 1.5081x; 1.1266x over previous
//
#include <hip/hip_runtime.h>
#include <hip/hip_bf16.h>
#include <cstdint>

// ---------------------------------------------------------------------------
// Qwen3.5 GatedDeltaNet — round 11:
//  * gemm256: T2 XOR-swizzle (pre-swizzled global source + swizzled ds_read,
//    linear LDS dest per rule #21) — kills the 16-lane/bank-quad conflict.
//  * out GEMM back to 128^2 gemm_mfma_f32 (512 blocks; 256^2 gave only 128).
//  All other kernels unchanged from round 10 (passed, absmax 0.0234).
// ---------------------------------------------------------------------------

#define HSZ 2048
#define NUM_K_HEADS 16
#define NUM_V_HEADS 32
#define DKH 128
#define DVH 128
#define KEY_DIM 2048
#define VALUE_DIM 4096
#define CONV_DIM 8192
#define BB 2
#define SSEQ 2048
#define MM (BB * SSEQ) /* 4096 rows */
#define CHUNK 64
#define NCHUNK (SSEQ / CHUNK) /* 32 */
#define DVB 16 /* v-cols per recur block */

typedef __hip_bfloat16 bf16;
typedef short short8 __attribute__((ext_vector_type(8)));
typedef float f32x4 __attribute__((ext_vector_type(4)));

__device__ __forceinline__ float bfu(ushort u) {
  union { float f; uint32_t i; } x;
  x.i = ((uint32_t)u) << 16;
  return x.f;
}
__device__ __forceinline__ ushort f2b(float f) {
  bf16 h = __float2bfloat16(f);
  return *reinterpret_cast<ushort*>(&h);
}

__device__ __forceinline__ void gload16(const void* g, const void* l) {
  __builtin_amdgcn_global_load_lds(
      (const __attribute__((address_space(1))) unsigned int*)g,
      (__attribute__((address_space(3))) unsigned int*)(const_cast<void*>(l)),
      16, 0, 0);
}

// swizzled LDS indexers (break D=128/D=64 row-major bank pathology)
__device__ __forceinline__ int kidx(int r, int d) {  // [*][128] bf16
  return r * 128 + (((d >> 3) ^ (r & 7)) << 3) + (d & 7);
}
__device__ __forceinline__ int widx(int r, int d) {  // [*][64] bf16
  return r * 64 + (((d >> 3) ^ (r & 7)) << 3) + (d & 7);
}

// ---------------- cast fp32 -> bf16 ----------------------------------------
__global__ __launch_bounds__(256) void cast_bf16_kernel(
    const float* __restrict__ in, ushort* __restrict__ out, int n4) {
  int i = blockIdx.x * 256 + threadIdx.x;
  if (i < n4) {
    float4 v = ((const float4*)in)[i];
    ushort4 u;
    u.x = f2b(v.x); u.y = f2b(v.y); u.z = f2b(v.z); u.w = f2b(v.w);
    ((ushort4*)out)[i] = u;
  }
}

// ---------------- transpose + cast: W[K,N] fp32 -> WT[N,K] bf16 ------------
__global__ __launch_bounds__(256) void transpose_cast(
    const float* __restrict__ W, ushort* __restrict__ WT, int K, int N) {
  __shared__ ushort tile[32][33];
  const int tx = threadIdx.x & 31, ty = threadIdx.x >> 5;
  const int n0 = blockIdx.x * 32, k0 = blockIdx.y * 32;
#pragma unroll
  for (int i = 0; i < 4; ++i)
    tile[ty + i * 8][tx] = f2b(W[(size_t)(k0 + ty + i * 8) * N + n0 + tx]);
  __syncthreads();
#pragma unroll
  for (int i = 0; i < 4; ++i)
    WT[(size_t)(n0 + ty + i * 8) * K + k0 + tx] = tile[tx][ty + i * 8];
}

// ---------------- 256^2 bf16 MFMA GEMM (bf16 out), T2-swizzled -------------
// 256x256 tile, BK=64, 512 thr (8 waves, 2Mx4N), per-wave 128x64 output.
// Counted-vmcnt double-buffered global_load_lds; LDS granule ^= row&7 swizzle
// applied on the GLOBAL SOURCE (stage) and the ds_read (compute) — LDS dest
// stays linear (rule #21: both-sides-or-neither with global_load_lds).
__global__ __launch_bounds__(512) void gemm256(
    const ushort* __restrict__ A, const ushort* __restrict__ BT,
    ushort* __restrict__ Cv, int M, int N, int K) {
  __shared__ __align__(16) ushort smem[256 * 264];  // 132 KiB
  const int t = threadIdx.x;
  const int w = t >> 6, lane = t & 63;
  const int m0 = blockIdx.y * 256, n0 = blockIdx.x * 256;
  const int wm = (w >> 2) * 128, wn = (w & 3) * 64;
  const int fr = lane & 15, kb = lane >> 4;
  const int srow = t >> 3;       // 0..63
  const int scol = (t & 7) * 8;  // bf16 col (16B granule)
  const int ssw = ((scol >> 3) ^ (srow & 7)) << 3;  // pre-swizzled src col
  const int rsw = fr & 7;                           // read-side row swizzle
  f32x4 acc[8][4] = {};
  const int nt = K / 64;

#define STAGE_TILE(tt, buf)                                                   \
  {                                                                           \
    const int k0_ = (tt)*64;                                                  \
    ushort* As_ = smem + (buf)*32768;                                         \
    ushort* Bs_ = As_ + 16384;                                                \
    _Pragma("unroll") for (int p = 0; p < 4; ++p) {                           \
      const int row_ = p * 64 + srow;                                         \
      gload16(&A[(size_t)(m0 + row_) * K + k0_ + ssw],                        \
              &As_[row_ * 64 + scol]);                                        \
    }                                                                         \
    _Pragma("unroll") for (int p = 0; p < 4; ++p) {                           \
      const int row_ = p * 64 + srow;                                         \
      gload16(&BT[(size_t)(n0 + row_) * K + k0_ + ssw],                       \
              &Bs_[row_ * 64 + scol]);                                        \
    }                                                                         \
  }

  STAGE_TILE(0, 0);
  STAGE_TILE(1, 1);

  for (int tt = 0; tt < nt; ++tt) {
    const int buf = tt & 1;
    const ushort* As = smem + buf * 32768;
    const ushort* Bs = As + 16384;
    if (tt + 1 < nt)
      asm volatile("s_waitcnt vmcnt(8)" ::: "memory");
    else
      asm volatile("s_waitcnt vmcnt(0)" ::: "memory");
    __builtin_amdgcn_sched_barrier(0);
    __builtin_amdgcn_s_barrier();  // all waves' tile-tt loads landed
    __builtin_amdgcn_sched_barrier(0);
#pragma unroll
    for (int ks = 0; ks < 2; ++ks) {
      const int kg = ks * 4 + kb;  // k-granule index 0..7
      const int ca = ((kg ^ rsw) << 3);
      short8 af[8], bf_[4];
#pragma unroll
      for (int mf = 0; mf < 8; ++mf)
        af[mf] = *(const short8*)&As[(wm + mf * 16 + fr) * 64 + ca];
#pragma unroll
      for (int nf = 0; nf < 4; ++nf)
        bf_[nf] = *(const short8*)&Bs[(wn + nf * 16 + fr) * 64 + ca];
#pragma unroll
      for (int mf = 0; mf < 8; ++mf)
#pragma unroll
        for (int nf = 0; nf < 4; ++nf)
          acc[mf][nf] = __builtin_amdgcn_mfma_f32_16x16x32_bf16(
              af[mf], bf_[nf], acc[mf][nf], 0, 0, 0);
    }
    __builtin_amdgcn_sched_barrier(0);
    __builtin_amdgcn_s_barrier();  // all waves done reading buf
    __builtin_amdgcn_sched_barrier(0);
    if (tt + 2 < nt) STAGE_TILE(tt + 2, buf);
  }
#undef STAGE_TILE

  const int crow = wm + (lane >> 4) * 4;
  const int ccol = wn + fr;
  // stage C in LDS [256][264], then coalesced short8 stores
#pragma unroll
  for (int mf = 0; mf < 8; ++mf)
#pragma unroll
    for (int nf = 0; nf < 4; ++nf)
#pragma unroll
      for (int j = 0; j < 4; ++j)
        smem[(crow + mf * 16 + j) * 264 + ccol + nf * 16] = f2b(acc[mf][nf][j]);
  __syncthreads();
#pragma unroll
  for (int p = 0; p < 16; ++p) {
    const int r = p * 16 + (t >> 5), cch = (t & 31) * 8;
    *(short8*)&Cv[(size_t)(m0 + r) * N + n0 + cch] =
        *(const short8*)&smem[r * 264 + cch];
  }
}

// ---------------- 128^2 bf16 MFMA GEMM (fp32 out) --------------------------
// Proven round-7 structure; used for the out GEMM (N=2048 -> 512 blocks).
__global__ __launch_bounds__(256) void gemm_mfma_f32(
    const ushort* __restrict__ A, const ushort* __restrict__ BT,
    float* __restrict__ C, int M, int N, int K) {
  __shared__ ushort As[128 * 64];
  __shared__ ushort Bs[128 * 64];
  const int t = threadIdx.x;
  const int w = t >> 6, lane = t & 63;
  const int m0 = blockIdx.y * 128, n0 = blockIdx.x * 128;
  const int srow = lane >> 3;
  const int scol = (lane & 7) * 8;
  const int wm = (w >> 1) * 64, wn = (w & 1) * 64;
  const int fr = lane & 15, kb = lane >> 4;
  f32x4 acc[4][4] = {};

  for (int k0 = 0; k0 < K; k0 += 64) {
#pragma unroll
    for (int i = 0; i < 4; ++i) {
      const int row = (i * 4 + w) * 8 + srow;
      gload16(&A[(size_t)(m0 + row) * K + k0 + scol], &As[row * 64 + scol]);
      gload16(&BT[(size_t)(n0 + row) * K + k0 + scol], &Bs[row * 64 + scol]);
    }
    __syncthreads();
#pragma unroll
    for (int ks = 0; ks < 2; ++ks) {
      const int ka = ks * 32 + kb * 8;
      short8 af[4], bfr[4];
#pragma unroll
      for (int mf = 0; mf < 4; ++mf)
        af[mf] = *(const short8*)&As[(wm + mf * 16 + fr) * 64 + ka];
#pragma unroll
      for (int nf = 0; nf < 4; ++nf)
        bfr[nf] = *(const short8*)&Bs[(wn + nf * 16 + fr) * 64 + ka];
#pragma unroll
      for (int mf = 0; mf < 4; ++mf)
#pragma unroll
        for (int nf = 0; nf < 4; ++nf)
          acc[mf][nf] = __builtin_amdgcn_mfma_f32_16x16x32_bf16(
              af[mf], bfr[nf], acc[mf][nf], 0, 0, 0);
    }
    __syncthreads();
  }
  const int orow = m0 + wm + (lane >> 4) * 4;
  const int ocol = n0 + wn + fr;
#pragma unroll
  for (int mf = 0; mf < 4; ++mf)
#pragma unroll
    for (int nf = 0; nf < 4; ++nf)
#pragma unroll
      for (int j = 0; j < 4; ++j)
        C[(size_t)(orow + mf * 16 + j) * N + ocol + nf * 16] = acc[mf][nf][j];
}

// ---------------- b/a projections + gates (8 rows/block) -------------------
__global__ __launch_bounds__(256) void ba_kernel(
    const float* __restrict__ hs, const float* __restrict__ w_b,
    const float* __restrict__ w_a, const float* __restrict__ dt_bias,
    const float* __restrict__ A_log, float* __restrict__ gbuf,
    float* __restrict__ beta) {
  const int row0 = blockIdx.x * 8;
  const int t = threadIdx.x;
  __shared__ float hsr[8][HSZ];  // 64 KB
  __shared__ float red[2][256];
  {
    const float4* src = (const float4*)(hs + (size_t)row0 * HSZ);
    for (int i = t; i < 8 * HSZ / 4; i += 256) ((float4*)hsr)[i] = src[i];
  }
  __syncthreads();
  const int h = t & 31, p = t >> 5;  // head, partial (8 over k)
  float sb[8] = {}, sa[8] = {};
  const int kbeg = p * 256;
  for (int k = kbeg; k < kbeg + 256; ++k) {
    float wb = w_b[k * NUM_V_HEADS + h];
    float wa = w_a[k * NUM_V_HEADS + h];
#pragma unroll
    for (int r = 0; r < 8; ++r) {
      float x = hsr[r][k];
      sb[r] += x * wb;
      sa[r] += x * wa;
    }
  }
#pragma unroll
  for (int r = 0; r < 8; ++r) {
    red[0][t] = sb[r];
    red[1][t] = sa[r];
    __syncthreads();
    if (t < NUM_V_HEADS) {
      float b = 0.f, a = 0.f;
#pragma unroll
      for (int q = 0; q < 8; ++q) {
        b += red[0][t + 32 * q];
        a += red[1][t + 32 * q];
      }
      float bet = 1.f / (1.f + expf(-b));
      float x = a + dt_bias[t];
      float sp = (x > 20.f) ? x : log1pf(expf(x));
      gbuf[(size_t)(row0 + r) * NUM_V_HEADS + t] = -expf(A_log[t]) * sp;
      beta[(size_t)(row0 + r) * NUM_V_HEADS + t] = bet;
    }
    __syncthreads();
  }
}

// ---------------- causal conv + silu + l2norm (bf16) -----------------------
__global__ __launch_bounds__(256) void conv_kernel(
    const ushort* __restrict__ mixed, const float* __restrict__ conv_w,
    ushort* __restrict__ qkv) {
  const int row = blockIdx.x;
  const int s = row & (SSEQ - 1);
  const int t = threadIdx.x;
  __shared__ float buf[CONV_DIM];
  const ushort* mrow = mixed + (size_t)row * CONV_DIM;
  for (int c = t; c < CONV_DIM; c += 256) {
    float accv = 0.f;
#pragma unroll
    for (int j = 0; j < 4; ++j) {
      int ds = s - 3 + j;
      if (ds >= 0)
        accv += bfu(mrow[(ptrdiff_t)(ds - s) * CONV_DIM + c]) * conv_w[c * 4 + j];
    }
    buf[c] = accv / (1.f + expf(-accv));
  }
  __syncthreads();
  const int grp = t >> 3, r = t & 7;
  const float* gp = buf + grp * DKH + r * 16;
  float ssq = 0.f;
#pragma unroll
  for (int i = 0; i < 16; ++i) {
    float x = gp[i];
    ssq += x * x;
  }
  ssq += __shfl_xor(ssq, 1, 64);
  ssq += __shfl_xor(ssq, 2, 64);
  ssq += __shfl_xor(ssq, 4, 64);
  float sc = rsqrtf(ssq + 1e-6f);
  if (grp < 16) sc *= 0.08838834764831845f;
  ushort* orow = qkv + (size_t)row * CONV_DIM;
#pragma unroll
  for (int i = 0; i < 16; ++i) orow[grp * DKH + r * 16 + i] = f2b(gp[i] * sc);
  for (int c = 2 * KEY_DIM + t; c < CONV_DIM; c += 256) orow[c] = f2b(buf[c]);
}

// ---------------- stage 1: per-chunk T = (I+A)^{-1} and W ------------------
// grid = 2048: c = bid&31, h = (bid>>5)&31, b = bid>>10. 256 thr.
__global__ __launch_bounds__(256) void chunk_T_kernel(
    const ushort* __restrict__ qkv, const float* __restrict__ gbuf,
    const float* __restrict__ beta, ushort* __restrict__ Tbuf,
    ushort* __restrict__ Wbuf) {
  const int bid = blockIdx.x;
  const int c = bid & 31;
  const int h = (bid >> 5) & 31;
  const int b = bid >> 10;
  const int hk = h >> 1;
  const int t = threadIdx.x;
  const int w = t >> 6, lane = t & 63;
  const int fr = lane & 15, fq = lane >> 4;

  __shared__ ushort Klds[64 * 128];           // 16 KB
  __shared__ ushort Qlds[64 * 128];           // 16 KB
  __shared__ __align__(16) float AT[64][68];  // 17.4 KB, AT[j][i] = A[i][j]
  __shared__ ushort Wlds[64 * 64];            // 8 KB (widx layout)
  __shared__ float Gs[64], Bsh[64];

  const int row0 = b * SSEQ + c * CHUNK;
  const int qcol = hk * DKH;
  const int kcol = KEY_DIM + hk * DKH;

#pragma unroll
  for (int r = 0; r < 4; ++r) {
    int vi = t + 256 * r;
    int row = vi >> 4, gr = vi & 15;
    const size_t gb = (size_t)(row0 + row) * CONV_DIM;
    *(short8*)&Klds[row * 128 + ((gr ^ (row & 7)) << 3)] =
        *(const short8*)&qkv[gb + kcol + gr * 8];
    *(short8*)&Qlds[row * 128 + ((gr ^ (row & 7)) << 3)] =
        *(const short8*)&qkv[gb + qcol + gr * 8];
  }
  if (t < 64) {
    float s = gbuf[(size_t)(row0 + t) * NUM_V_HEADS + h];
#pragma unroll
    for (int off = 1; off < 64; off <<= 1) {
      float p = __shfl_up(s, off, 64);
      if (lane >= off) s += p;
    }
    Gs[t] = s;
    Bsh[t] = beta[(size_t)(row0 + t) * NUM_V_HEADS + h];
  }
  __syncthreads();

  // KK^T -> AT ; QK^T -> Wlds
  f32x4 kkt[4] = {}, qkt[4] = {};
#pragma unroll
  for (int ks = 0; ks < 4; ++ks) {
    int d0 = ks * 32 + fq * 8;
    short8 xk = *(const short8*)&Klds[kidx(w * 16 + fr, d0)];
    short8 xq = *(const short8*)&Qlds[kidx(w * 16 + fr, d0)];
#pragma unroll
    for (int j = 0; j < 4; ++j) {
      short8 yk = *(const short8*)&Klds[kidx(j * 16 + fr, d0)];
      kkt[j] = __builtin_amdgcn_mfma_f32_16x16x32_bf16(xk, yk, kkt[j], 0, 0, 0);
      qkt[j] = __builtin_amdgcn_mfma_f32_16x16x32_bf16(xq, yk, qkt[j], 0, 0, 0);
    }
  }
#pragma unroll
  for (int j = 0; j < 4; ++j)
#pragma unroll
    for (int jj = 0; jj < 4; ++jj) {
      int i = w * 16 + fq * 4 + jj;
      int jc = j * 16 + fr;
      AT[jc][i] = (jc < i) ? Bsh[i] * __expf(Gs[i] - Gs[jc]) * kkt[j][jj] : 0.f;
      float val = (jc <= i) ? __expf(Gs[i] - Gs[jc]) * qkt[j][jj] : 0.f;
      Wlds[widx(i, jc)] = f2b(val);
    }
  __syncthreads();

  // dump W (coalesced; layout already widx-swizzled)
  {
    ushort* Wg = Wbuf + (size_t)bid * 4096;
#pragma unroll
    for (int e = 0; e < 8; ++e)
      ((uint*)Wg)[e * 256 + t] = ((const uint*)Wlds)[e * 256 + t];
  }

  // wave 0: in-register forward substitution, lane = column of T
  if (w == 0) {
    float u[64];
#pragma unroll
    for (int i = 0; i < 64; ++i) u[i] = (i == lane) ? 1.f : 0.f;
#pragma unroll
    for (int j = 0; j < 63; ++j) {
      float xj = u[j];
      const int i0 = (j + 1) & ~3;
#pragma unroll
      for (int ii = i0; ii < 64; ii += 4) {
        float4 a4 = *(const float4*)&AT[j][ii];  // broadcast, aligned
        if (ii + 0 > j) u[ii + 0] -= a4.x * xj;
        if (ii + 1 > j) u[ii + 1] -= a4.y * xj;
        if (ii + 2 > j) u[ii + 2] -= a4.z * xj;
        if (ii + 3 > j) u[ii + 3] -= a4.w * xj;
      }
    }
    ushort* Tg = Tbuf + (size_t)bid * 4096;
#pragma unroll
    for (int i = 0; i < 64; ++i) Tg[i * 64 + lane] = f2b(u[i]);  // coalesced
  }
}

// ---------------- stage 2: sequential chunk loop (no solve, no QK^T) -------
// grid = 512: (b:2) x (h:32) x (dvq:8, DVB=16). 256 thr, 2 blocks/CU.
__global__ __launch_bounds__(256, 2) void recur_chunk_kernel(
    const ushort* __restrict__ qkv, const float* __restrict__ gbuf,
    const float* __restrict__ beta, const ushort* __restrict__ Tbuf,
    const ushort* __restrict__ Wbuf, float* __restrict__ o) {
  const int bid = blockIdx.x;
  const int dvq = bid & 7;
  const int h = (bid >> 3) & 31;
  const int b = bid >> 8;
  const int hk = h >> 1;
  const int t = threadIdx.x;
  const int w = t >> 6, lane = t & 63;
  const int fr = lane & 15, fq = lane >> 4;

  __shared__ ushort Klds[64 * 128];  // 16 KB
  __shared__ ushort Vlds[64 * DVB];  // 2 KB
  __shared__ ushort Sth[DVB * 128];  // 4 KB  S0^T hi
  __shared__ ushort Stl[DVB * 128];  // 4 KB  S0^T lo
  __shared__ ushort Th[64 * 64];     // 8 KB  T (widx)
  __shared__ ushort Wlds[64 * 64];   // 8 KB  W (widx, precomputed)
  __shared__ ushort Ut[DVB * 64];    // 2 KB  RHS^T (widx)
  __shared__ ushort UTs[DVB * 64];   // 2 KB  exp(G63-Gi)*u
  __shared__ ushort UTo[DVB * 64];   // 2 KB  plain u
  __shared__ float Gs[64], Bsh[64];

  float sreg[2][4] = {};  // S[(w*2+dt)*16 + fq*4 + jj][fr]

  const int qcol = hk * DKH;
  const int kcol = KEY_DIM + hk * DKH;
  const int vcol = 2 * KEY_DIM + h * DVH + dvq * DVB;
  const int ocol = h * DVH + dvq * DVB;
  const size_t tbase0 = ((size_t)(b * 32 + h) * 32) * 4096;

  for (int c = 0; c < NCHUNK; ++c) {
    const int row0 = b * SSEQ + c * CHUNK;

    // ---- P1: Q->regs, T/W->LDS, K/V->LDS, gates, S->hi/lo ----------------
    short8 xq[4];
#pragma unroll
    for (int ks = 0; ks < 4; ++ks)
      xq[ks] = *(const short8*)&qkv[(size_t)(row0 + w * 16 + fr) * CONV_DIM +
                                    qcol + ks * 32 + fq * 8];
    const ushort* Tg = Tbuf + tbase0 + (size_t)c * 4096;
    const ushort* Wg = Wbuf + tbase0 + (size_t)c * 4096;
    short8 tv0 = *(const short8*)&Tg[t * 16];
    short8 tv1 = *(const short8*)&Tg[t * 16 + 8];
#pragma unroll
    for (int e = 0; e < 8; ++e)
      ((uint*)Wlds)[e * 256 + t] = ((const uint*)Wg)[e * 256 + t];
#pragma unroll
    for (int r = 0; r < 4; ++r) {
      int vi = t + 256 * r;
      int row = vi >> 4, gr = vi & 15;
      *(short8*)&Klds[row * 128 + ((gr ^ (row & 7)) << 3)] =
          *(const short8*)&qkv[(size_t)(row0 + row) * CONV_DIM + kcol + gr * 8];
    }
    if (t < 128) {
      int row = t >> 1, c0 = (t & 1) * 8;
      *(short8*)&Vlds[row * DVB + c0] =
          *(const short8*)&qkv[(size_t)(row0 + row) * CONV_DIM + vcol + c0];
    }
    if (t < 64) {
      float s = gbuf[(size_t)(row0 + t) * NUM_V_HEADS + h];
#pragma unroll
      for (int off = 1; off < 64; off <<= 1) {
        float p = __shfl_up(s, off, 64);
        if (lane >= off) s += p;
      }
      Gs[t] = s;
      Bsh[t] = beta[(size_t)(row0 + t) * NUM_V_HEADS + h];
    }
#pragma unroll
    for (int dt = 0; dt < 2; ++dt)
#pragma unroll
      for (int jj = 0; jj < 4; ++jj) {
        int d = (w * 2 + dt) * 16 + fq * 4 + jj;
        float f = sreg[dt][jj];
        ushort hi = f2b(f);
        int idx = kidx(fr, d);
        Sth[idx] = hi;
        Stl[idx] = f2b(f - bfu(hi));
      }
    {
      int r = t >> 2, d0 = (t & 3) * 16;
      *(short8*)&Th[widx(r, d0)] = tv0;
      *(short8*)&Th[widx(r, d0 + 8)] = tv1;
    }
    __syncthreads();  // B1

    // ---- P2: ks0, qs0; RHS -> Ut; oacc init ------------------------------
    f32x4 ks0 = {}, qs0 = {};
#pragma unroll
    for (int ks = 0; ks < 4; ++ks) {
      int d0 = ks * 32 + fq * 8;
      short8 xk = *(const short8*)&Klds[kidx(w * 16 + fr, d0)];
      short8 yh = *(const short8*)&Sth[kidx(fr, d0)];
      short8 yl = *(const short8*)&Stl[kidx(fr, d0)];
      ks0 = __builtin_amdgcn_mfma_f32_16x16x32_bf16(xk, yh, ks0, 0, 0, 0);
      ks0 = __builtin_amdgcn_mfma_f32_16x16x32_bf16(xk, yl, ks0, 0, 0, 0);
      qs0 = __builtin_amdgcn_mfma_f32_16x16x32_bf16(xq[ks], yh, qs0, 0, 0, 0);
      qs0 = __builtin_amdgcn_mfma_f32_16x16x32_bf16(xq[ks], yl, qs0, 0, 0, 0);
    }
    f32x4 oacc;
#pragma unroll
    for (int jj = 0; jj < 4; ++jj) {
      int i = w * 16 + fq * 4 + jj;
      float eg = __expf(Gs[i]);
      float rhs = Bsh[i] * (bfu(Vlds[i * DVB + fr]) - eg * ks0[jj]);
      Ut[widx(fr, i)] = f2b(rhs);
      oacc[jj] = qs0[jj] * eg;
    }
    __syncthreads();  // B2

    // ---- P3: U = Th @ Ut (MFMA); write UTo / UTs -------------------------
    {
      f32x4 uacc = {};
#pragma unroll
      for (int ks = 0; ks < 2; ++ks) {
        int j0 = ks * 32 + fq * 8;
        short8 ta = *(const short8*)&Th[widx(w * 16 + fr, j0)];
        short8 ub = *(const short8*)&Ut[widx(fr, j0)];
        uacc = __builtin_amdgcn_mfma_f32_16x16x32_bf16(ta, ub, uacc, 0, 0, 0);
      }
#pragma unroll
      for (int jj = 0; jj < 4; ++jj) {
        int i = w * 16 + fq * 4 + jj;
        float u = uacc[jj];
        UTo[widx(fr, i)] = f2b(u);
        UTs[widx(fr, i)] = f2b(u * __expf(Gs[63] - Gs[i]));
      }
    }
    __syncthreads();  // B3

    // ---- P4: O = oacc + W@U; store; S := e^G63 S + K^T @ Us --------------
#pragma unroll
    for (int ks = 0; ks < 2; ++ks) {
      int i0 = ks * 32 + fq * 8;
      short8 xw = *(const short8*)&Wlds[widx(w * 16 + fr, i0)];
      short8 yu = *(const short8*)&UTo[widx(fr, i0)];
      oacc = __builtin_amdgcn_mfma_f32_16x16x32_bf16(xw, yu, oacc, 0, 0, 0);
    }
#pragma unroll
    for (int jj = 0; jj < 4; ++jj) {
      int tt = w * 16 + fq * 4 + jj;
      o[(size_t)(row0 + tt) * VALUE_DIM + ocol + fr] = oacc[jj];
    }
    {
      float eGC = __expf(Gs[63]);
#pragma unroll
      for (int dt = 0; dt < 2; ++dt) {
        const int dk0 = (w * 2 + dt) * 16;
        f32x4 sacc;
#pragma unroll
        for (int jj = 0; jj < 4; ++jj) sacc[jj] = sreg[dt][jj] * eGC;
        const int dkr = dk0 + fr;
#pragma unroll
        for (int ks = 0; ks < 2; ++ks) {
          short8 xk;
#pragma unroll
          for (int e = 0; e < 8; ++e)
            xk[e] = (short)Klds[kidx(ks * 32 + fq * 8 + e, dkr)];
          short8 yu = *(const short8*)&UTs[widx(fr, ks * 32 + fq * 8)];
          sacc = __builtin_amdgcn_mfma_f32_16x16x32_bf16(xk, yu, sacc, 0, 0, 0);
        }
#pragma unroll
        for (int jj = 0; jj < 4; ++jj) sreg[dt][jj] = sacc[jj];
      }
    }
    __syncthreads();  // B4 (protect LDS for next chunk's P1)
  }
}

// ---------------- gated RMSNorm -> bf16 ------------------------------------
__global__ __launch_bounds__(256) void gnorm_kernel(
    const float* __restrict__ o, const ushort* __restrict__ z,
    const float* __restrict__ gamma, ushort* __restrict__ ob) {
  const int row = blockIdx.x;
  const int t = threadIdx.x;
  const int grp = t >> 3, r = t & 7;
  const float* op = o + (size_t)row * VALUE_DIM + grp * DVH + r * 16;
  const ushort* zp = z + (size_t)row * VALUE_DIM + grp * DVH + r * 16;
  ushort* obp = ob + (size_t)row * VALUE_DIM + grp * DVH + r * 16;
  float vals[16];
  float ssq = 0.f;
#pragma unroll
  for (int i = 0; i < 16; ++i) {
    float zz = bfu(zp[i]);
    float x = op[i] * (zz / (1.f + expf(-zz)));
    vals[i] = x;
    ssq += x * x;
  }
  ssq += __shfl_xor(ssq, 1, 64);
  ssq += __shfl_xor(ssq, 2, 64);
  ssq += __shfl_xor(ssq, 4, 64);
  float sc = rsqrtf(ssq * (1.f / 128.f) + 1e-6f);
#pragma unroll
  for (int i = 0; i < 16; ++i) obp[i] = f2b(vals[i] * sc * gamma[r * 16 + i]);
}

// ---------------------------------------------------------------------------
extern "C" void kernel_launch(void* const* d_in, const int* in_sizes, int n_in,
                              void* d_out, int out_size, void* d_ws,
                              size_t ws_size, hipStream_t stream) {
  const float* hs = (const float*)d_in[0];
  const float* w_qkv = (const float*)d_in[1];
  const float* w_z = (const float*)d_in[2];
  const float* w_b = (const float*)d_in[3];
  const float* w_a = (const float*)d_in[4];
  const float* conv_w = (const float*)d_in[5];
  const float* dt_bias = (const float*)d_in[6];
  const float* A_log = (const float*)d_in[7];
  const float* gamma = (const float*)d_in[8];
  const float* w_out = (const float*)d_in[9];
  float* out = (float*)d_out;
  char* wsb = (char*)d_ws;

  // workspace layout (241 MiB total)
  ushort* hs_b = (ushort*)wsb;                      // 16 MiB (later: Tbuf)
  ushort* wqkvT = hs_b + (size_t)MM * HSZ;          // 32 MiB (later: Wbuf)
  ushort* wzT = wqkvT + (size_t)CONV_DIM * HSZ;     // 16 MiB
  ushort* woutT = wzT + (size_t)VALUE_DIM * HSZ;    // 16 MiB
  ushort* mixed = woutT + (size_t)HSZ * VALUE_DIM;  // 64 MiB bf16
  ushort* qkv = mixed + (size_t)MM * CONV_DIM;      // 64 MiB bf16
  ushort* z = qkv + (size_t)MM * CONV_DIM;          // 32 MiB bf16
  float* gbuf = (float*)(z + (size_t)MM * VALUE_DIM);
  float* beta = gbuf + (size_t)MM * NUM_V_HEADS;
  float* o = (float*)mixed;   // fp32, aliases retired mixed (64 MiB)
  ushort* ob = qkv;           // bf16, aliases retired qkv
  ushort* Tbuf = hs_b;        // 16 MiB, aliases retired hs_b
  ushort* Wbuf = wqkvT;       // 16 MiB, aliases retired wqkvT

  cast_bf16_kernel<<<(MM * HSZ / 4 + 255) / 256, 256, 0, stream>>>(
      hs, hs_b, MM * HSZ / 4);
  transpose_cast<<<dim3(CONV_DIM / 32, HSZ / 32), 256, 0, stream>>>(
      w_qkv, wqkvT, HSZ, CONV_DIM);
  transpose_cast<<<dim3(VALUE_DIM / 32, HSZ / 32), 256, 0, stream>>>(
      w_z, wzT, HSZ, VALUE_DIM);
  transpose_cast<<<dim3(HSZ / 32, VALUE_DIM / 32), 256, 0, stream>>>(
      w_out, woutT, VALUE_DIM, HSZ);

  gemm256<<<dim3(CONV_DIM / 256, MM / 256), 512, 0, stream>>>(
      hs_b, wqkvT, mixed, MM, CONV_DIM, HSZ);
  gemm256<<<dim3(VALUE_DIM / 256, MM / 256), 512, 0, stream>>>(
      hs_b, wzT, z, MM, VALUE_DIM, HSZ);
  ba_kernel<<<MM / 8, 256, 0, stream>>>(hs, w_b, w_a, dt_bias, A_log, gbuf,
                                        beta);
  conv_kernel<<<MM, 256, 0, stream>>>(mixed, conv_w, qkv);
  chunk_T_kernel<<<2048, 256, 0, stream>>>(qkv, gbuf, beta, Tbuf, Wbuf);
  recur_chunk_kernel<<<512, 256, 0, stream>>>(qkv, gbuf, beta, Tbuf, Wbuf, o);
  gnorm_kernel<<<MM, 256, 0, stream>>>(o, z, gamma, ob);
  gemm_mfma_f32<<<dim3(HSZ / 128, MM / 128), 256, 0, stream>>>(
      ob, woutT, out, MM, HSZ, VALUE_DIM);
}